// Round 10
// baseline (324.954 us; speedup 1.0000x reference)
//
#include <hip/hip_runtime.h>
#include <hip/hip_bf16.h>
#include <stdint.h>
#include <math.h>

#define DIMC 1024
#define SEQ 1024
#define NBATCH 8
#define NHEADS 16
#define HDIM 64
#define MLPHID 4096
#define NROWS (NBATCH*SEQ)

typedef __attribute__((ext_vector_type(8))) short short8;
typedef __attribute__((ext_vector_type(4))) float f32x4;
typedef __attribute__((ext_vector_type(16))) float f32x16;
typedef __attribute__((ext_vector_type(4))) unsigned int u32x4;

__device__ __forceinline__ short f2bf(float f) {
  union { float f; uint32_t u; } x; x.f = f;
  uint32_t r = (x.u + 0x7FFFu + ((x.u >> 16) & 1u)) >> 16;
  return (short)r;
}

__device__ __forceinline__ float bf2f(unsigned short b) {
  union { uint32_t u; float f; } c; c.u = ((uint32_t)b) << 16;
  return c.f;
}

__device__ __forceinline__ unsigned int cvtpk(float lo, float hi_) {
  unsigned int r;
  asm("v_cvt_pk_bf16_f32 %0, %1, %2" : "=v"(r) : "v"(lo), "v"(hi_));
  return r;
}

// tanh-form GELU via hw exp2 + rcp
__device__ __forceinline__ float gelu_f(float v) {
  const float t = v * v;
  const float p = fmaf(t, 0.044715f, 1.0f);
  const float e = __builtin_amdgcn_exp2f(2.3022082f * v * p);
  return v - v * __builtin_amdgcn_rcpf(e + 1.0f);
}

__device__ __forceinline__ f32x4 mfma16(short8 a, short8 b, f32x4 c) {
  return __builtin_amdgcn_mfma_f32_16x16x32_bf16(a, b, c, 0, 0, 0);
}
__device__ __forceinline__ f32x16 mfma32(short8 a, short8 b, f32x16 c) {
  return __builtin_amdgcn_mfma_f32_32x32x16_bf16(a, b, c, 0, 0, 0);
}

__device__ __forceinline__ void gload16(const void* g, void* l) {
  __builtin_amdgcn_global_load_lds(
      (const __attribute__((address_space(1))) uint32_t*)g,
      (__attribute__((address_space(3))) uint32_t*)l, 16, 0, 0);
}

// -------- merged prep: LN1 (blocks 0..8191) + weight converts (8192..20479) --------
__global__ __launch_bounds__(256)
void prep_kernel(const float* __restrict__ x, const float* __restrict__ g,
                 const float* __restrict__ beta, short* __restrict__ hb,
                 const float* __restrict__ w0, const float* __restrict__ w1,
                 const float* __restrict__ w2, const float* __restrict__ w3,
                 short* __restrict__ o0, short* __restrict__ o1,
                 short* __restrict__ o2, short* __restrict__ o3) {
  const int tid = threadIdx.x;
  if (blockIdx.x < NROWS) {
    const int row = blockIdx.x;
    const float4 v = ((const float4*)(x + (size_t)row * DIMC))[tid];
    float s = v.x + v.y + v.z + v.w;
    float q = v.x*v.x + v.y*v.y + v.z*v.z + v.w*v.w;
#pragma unroll
    for (int o = 32; o > 0; o >>= 1) { s += __shfl_down(s, o); q += __shfl_down(q, o); }
    __shared__ float rs[4], rq[4];
    const int lane = tid & 63, w = tid >> 6;
    if (lane == 0) { rs[w] = s; rq[w] = q; }
    __syncthreads();
    s = rs[0] + rs[1] + rs[2] + rs[3];
    q = rq[0] + rq[1] + rq[2] + rq[3];
    const float mean = s * (1.0f / DIMC);
    const float var = q * (1.0f / DIMC) - mean * mean;
    const float rstd = rsqrtf(var + 1e-5f);
    const float4 gv = ((const float4*)g)[tid];
    const float4 bv = ((const float4*)beta)[tid];
    short4 o4;
    o4.x = f2bf((v.x - mean) * rstd * gv.x + bv.x);
    o4.y = f2bf((v.y - mean) * rstd * gv.y + bv.y);
    o4.z = f2bf((v.z - mean) * rstd * gv.z + bv.z);
    o4.w = f2bf((v.w - mean) * rstd * gv.w + bv.w);
    ((short4*)(hb + (size_t)row * DIMC))[tid] = o4;
  } else {
    const int i = (blockIdx.x - NROWS) * 256 + tid;
    const float4* src;
    short4* dst;
    if (i < 786432)       { src = (const float4*)w0 + i;             dst = (short4*)o0 + i; }
    else if (i < 1048576) { src = (const float4*)w1 + (i - 786432);  dst = (short4*)o1 + (i - 786432); }
    else if (i < 2097152) { src = (const float4*)w2 + (i - 1048576); dst = (short4*)o2 + (i - 1048576); }
    else                  { src = (const float4*)w3 + (i - 2097152); dst = (short4*)o3 + (i - 2097152); }
    const float4 v = *src;
    short4 o;
    o.x = f2bf(v.x); o.y = f2bf(v.y); o.z = f2bf(v.z); o.w = f2bf(v.w);
    *dst = o;
  }
}

// ---------------- LayerNorm (row = 1024), bf16 input -> bf16 ----------------
template<bool INBF16>
__global__ __launch_bounds__(256)
void ln_kernel(const void* __restrict__ xin, const float* __restrict__ g,
               const float* __restrict__ beta, short* __restrict__ out) {
  const int row = blockIdx.x;
  const int tid = threadIdx.x;
  float4 v;
  if (INBF16) {
    const short4 vb = ((const short4*)xin)[row * 256 + tid];
    v.x = bf2f((unsigned short)vb.x); v.y = bf2f((unsigned short)vb.y);
    v.z = bf2f((unsigned short)vb.z); v.w = bf2f((unsigned short)vb.w);
  } else {
    v = ((const float4*)xin)[row * 256 + tid];
  }
  float s = v.x + v.y + v.z + v.w;
  float q = v.x*v.x + v.y*v.y + v.z*v.z + v.w*v.w;
#pragma unroll
  for (int o = 32; o > 0; o >>= 1) { s += __shfl_down(s, o); q += __shfl_down(q, o); }
  __shared__ float rs[4], rq[4];
  const int lane = tid & 63, w = tid >> 6;
  if (lane == 0) { rs[w] = s; rq[w] = q; }
  __syncthreads();
  s = rs[0] + rs[1] + rs[2] + rs[3];
  q = rq[0] + rq[1] + rq[2] + rq[3];
  const float mean = s * (1.0f / DIMC);
  const float var = q * (1.0f / DIMC) - mean * mean;
  const float rstd = rsqrtf(var + 1e-5f);
  const float4 gv = ((const float4*)g)[tid];
  const float4 bv = ((const float4*)beta)[tid];
  short4 o4;
  o4.x = f2bf((v.x - mean) * rstd * gv.x + bv.x);
  o4.y = f2bf((v.y - mean) * rstd * gv.y + bv.y);
  o4.z = f2bf((v.z - mean) * rstd * gv.z + bv.z);
  o4.w = f2bf((v.w - mean) * rstd * gv.w + bv.w);
  ((short4*)(out + (size_t)row * DIMC))[tid] = o4;
}

// ======================= GEMM engines =======================
// Region subtile layout: [16r][32k] bf16 (1024B), st_16x32 swizzle (byte col
// ^= ((r16>>3)&1)<<5), staged linearly via global_load_lds from pre-swizzled
// global source; ds_read applies the same involution.

#define NOVM ((void)0)
#define NOST ((void)0)
#define VMC4 asm volatile("s_waitcnt vmcnt(4)" ::: "memory")
#define VMC2 asm volatile("s_waitcnt vmcnt(2)" ::: "memory")

// ---------- gemm8p (FC1 control): BM=256/BN=256, 8 waves 2Mx4N, LDS 128KB ----------
#define SA(DB, H, T) \
  gload16(sA0 + (H)*hstep + (size_t)(T)*64, stb + ((DB)*4 + (H))*16384); \
  gload16(sA1 + (H)*hstep + (size_t)(T)*64, stb + ((DB)*4 + (H))*16384 + 8192)

#define SB(DB, H, T) \
  gload16(sB0 + (H)*hstep + (size_t)(T)*64, stb + ((DB)*4 + 2 + (H))*16384); \
  gload16(sB1 + (H)*hstep + (size_t)(T)*64, stb + ((DB)*4 + 2 + (H))*16384 + 8192)

#define PH(DB, QA, QB, LDA, LDB, STAGE, VM) \
  do { \
    if (LDA) { \
      _Pragma("unroll") \
      for (int mi = 0; mi < 4; ++mi) { \
        _Pragma("unroll") \
        for (int ks = 0; ks < 2; ++ks) \
          af[mi][ks] = *(const short8*)(ard##DB + (((QA)*4 + mi)*2 + ks)*1024); \
      } \
    } \
    if (LDB) { \
      _Pragma("unroll") \
      for (int ni = 0; ni < 2; ++ni) { \
        _Pragma("unroll") \
        for (int ks = 0; ks < 2; ++ks) \
          bfv[QB][ni][ks] = *(const short8*)(brd##DB + (((QB)*2 + ni)*2 + ks)*1024); \
      } \
    } \
    STAGE; \
    __builtin_amdgcn_s_barrier(); \
    asm volatile("s_waitcnt lgkmcnt(0)" ::: "memory"); \
    __builtin_amdgcn_sched_barrier(0); \
    __builtin_amdgcn_s_setprio(1); \
    _Pragma("unroll") \
    for (int ks = 0; ks < 2; ++ks) { \
      _Pragma("unroll") \
      for (int mi = 0; mi < 4; ++mi) { \
        _Pragma("unroll") \
        for (int ni = 0; ni < 2; ++ni) \
          acc[(QA)*4 + mi][(QB)*2 + ni] = \
            mfma16(af[mi][ks], bfv[QB][ni][ks], acc[(QA)*4 + mi][(QB)*2 + ni]); \
      } \
    } \
    __builtin_amdgcn_s_setprio(0); \
    VM; \
    __builtin_amdgcn_s_barrier(); \
  } while (0)

template<bool BIAS, bool GELU, bool RESID, bool OBF16>
__global__ __launch_bounds__(512)
void gemm8p(const short* __restrict__ A, const short* __restrict__ W,
            const float* __restrict__ bias, const float* __restrict__ resid,
            float* __restrict__ outF, short* __restrict__ outB,
            int M, int N, int K, int ntl, int mt8)
{
  __shared__ __align__(16) char lsm[131072];
  const int tid = threadIdx.x;
  const int lane = tid & 63;
  const int w = tid >> 6;
  const int wm = w >> 2;
  const int wn = w & 3;
  const int fr = lane & 15;
  const int fko = (lane >> 4) << 3;

  const int bid = blockIdx.x;
  const int xcd = bid & 7, l = bid >> 3;
  const int bm = (xcd * mt8 + l / ntl) << 8;
  const int bn = (l % ntl) << 8;

  int row_[2], kk_[2];
#pragma unroll
  for (int j = 0; j < 2; ++j) {
    const int s = j * 8 + (tid >> 6);
    const int r16 = (tid & 63) >> 2;
    const int cb = ((tid & 3) << 4) ^ (((tid >> 5) & 1) << 5);
    row_[j] = (s >> 1) * 16 + r16;
    kk_[j]  = (s & 1) * 32 + (cb >> 1);
  }
  const short* sA0 = A + (size_t)(bm + row_[0]) * K + kk_[0];
  const short* sA1 = A + (size_t)(bm + row_[1]) * K + kk_[1];
  const short* sB0 = W + (size_t)(bn + row_[0]) * K + kk_[0];
  const short* sB1 = W + (size_t)(bn + row_[1]) * K + kk_[1];
  const size_t hstep = (size_t)128 * K;
  char* stb = lsm + tid * 16;

  const int lofs = fr * 64 + ((fko << 1) ^ (((fr >> 3) & 1) << 5));
  const char* ard0 = lsm + wm * 16384 + lofs;
  const char* brd0 = lsm + 32768 + (wn >> 1) * 16384 + (wn & 1) * 8192 + lofs;
  const char* ard1 = ard0 + 65536;
  const char* brd1 = brd0 + 65536;

  short8 af[4][2];
  short8 bfv[2][2][2];
  f32x4 acc[8][4] = {};

  SA(0, 0, 0); SA(0, 1, 0);
  SB(0, 0, 0); SB(0, 1, 0);
  SB(1, 0, 1); SB(1, 1, 1);
  VMC4;
  __builtin_amdgcn_s_barrier();

  const int nk = K >> 6;
  const int nit = nk >> 1;
  const int tmask = nk - 1;
  for (int it = 0; it < nit; ++it) {
    const int t1 = 2 * it + 1;
    const int t2 = (2 * it + 2) & tmask;
    const int t3 = (2 * it + 3) & tmask;
    PH(0, 0, 0, 1, 1, SA(1, 0, t1), NOVM);
    PH(0, 0, 1, 0, 1, SA(1, 1, t1), NOVM);
    PH(0, 1, 1, 1, 0, SB(0, 0, t2), NOVM);
    PH(0, 1, 0, 0, 0, SB(0, 1, t2), VMC4);
    PH(1, 0, 0, 1, 1, SA(0, 0, t2), NOVM);
    PH(1, 0, 1, 0, 1, SA(0, 1, t2), NOVM);
    PH(1, 1, 1, 1, 0, SB(1, 0, t3), NOVM);
    PH(1, 1, 0, 0, 0, SB(1, 1, t3), VMC4);
  }

  asm volatile("s_waitcnt vmcnt(0)" ::: "memory");
  __builtin_amdgcn_s_barrier();

  const int orow0 = bm + wm * 128 + ((lane >> 4) << 2);
  const int ocol0 = bn + wn * 64 + fr;
#pragma unroll
  for (int mi = 0; mi < 8; ++mi) {
#pragma unroll
    for (int r = 0; r < 4; ++r) {
      const int row = orow0 + mi * 16 + r;
      const size_t base = (size_t)row * N;
#pragma unroll
      for (int ni = 0; ni < 4; ++ni) {
        const int col = ocol0 + ni * 16;
        float v = acc[mi][ni][r];
        if (BIAS) v += bias[col];
        if (GELU) v = gelu_f(v);
        if (RESID) v += resid[base + col];
        if (OBF16) outB[base + col] = f2bf(v);
        else       outF[base + col] = v;
      }
    }
  }
}

// ---------- gemm2k: BM=256/BN=128, by-ks phases (16 MFMA + 8 ds_read/phase) ----------
// 8 waves 4Mx2N (64x64/wave), 2 phases/K-tile. LDS 112KB:
//   A slots 2x32KB @0/@32768 (slot = tile&1), B ring 3x16KB @65536 (slot = tile%3).
// Pair i computes u=2i (ph1-2, A-slot0/B-slot u%3), v=2i+1 (ph3-4, A-slot1/B v%3).
// Stage: ph1 A@v->slot1, ph2 B@u+2->w-slot + vmcnt(2), ph3 A@u+2->slot0,
//        ph4 B@v+2->u-slot + vmcnt(2).
// FIFO induction (steady state): ph2's VMC2 leaves {B@u+2}, drains A@v (read ph3);
// ph4's VMC2 leaves {B@v+2}, drains {B@u+2? no—drains A@u+2 and B@u... see below}:
//   issue order ...A@v(4),B@u+2(2),A@u+2(4),B@v+2(2)...; each VMC2 keeps newest 2.
//   Every LDS read is covered; every stage targets a slot read >=1 barrier earlier.
#define SAK(SLOT, T) \
  gload16(sA0 + (size_t)(T)*64,         (SLOT) + tid*16); \
  gload16(sA1 + (size_t)(T)*64,         (SLOT) + 8192 + tid*16); \
  gload16(sA0 + hstep + (size_t)(T)*64, (SLOT) + 16384 + tid*16); \
  gload16(sA1 + hstep + (size_t)(T)*64, (SLOT) + 24576 + tid*16)

#define SBK(SLOT, T) \
  gload16(sB0 + (size_t)(T)*64, (SLOT) + tid*16); \
  gload16(sB1 + (size_t)(T)*64, (SLOT) + 8192 + tid*16)

#define PHK(ARD, BRD, KS, STAGE, VM) \
  do { \
    _Pragma("unroll") \
    for (int mi = 0; mi < 4; ++mi) \
      af[mi] = *(const short8*)((ARD) + (mi*2 + (KS))*1024); \
    _Pragma("unroll") \
    for (int jn = 0; jn < 4; ++jn) \
      bfq[jn] = *(const short8*)((BRD) + (jn*2 + (KS))*1024); \
    STAGE; \
    __builtin_amdgcn_s_barrier(); \
    asm volatile("s_waitcnt lgkmcnt(0)" ::: "memory"); \
    __builtin_amdgcn_sched_barrier(0); \
    __builtin_amdgcn_s_setprio(1); \
    _Pragma("unroll") \
    for (int mi = 0; mi < 4; ++mi) { \
      _Pragma("unroll") \
      for (int jn = 0; jn < 4; ++jn) \
        acc[mi][jn] = mfma16(af[mi], bfq[jn], acc[mi][jn]); \
    } \
    __builtin_amdgcn_s_setprio(0); \
    VM; \
    __builtin_amdgcn_s_barrier(); \
  } while (0)

template<bool BIAS, bool GELU, bool RESID, bool RESB16, bool OBF16, bool QSCALE>
__global__ __launch_bounds__(512)
void gemm2k(const short* __restrict__ A, const short* __restrict__ W,
            const float* __restrict__ bias, const void* __restrict__ resid,
            float* __restrict__ outF, short* __restrict__ outB,
            int M, int N, int K, int ntl, int mt8)
{
  __shared__ __align__(16) char lsm[114688];
  const int tid = threadIdx.x;
  const int lane = tid & 63;
  const int w = tid >> 6;
  const int wm = w >> 1;          // 0..3 -> 64-row strip
  const int wn = w & 1;           // 0..1 -> 64-col strip
  const int fr = lane & 15;
  const int fko = (lane >> 4) << 3;

  const int bid = blockIdx.x;
  const int xcd = bid & 7, l = bid >> 3;
  const int bm = (xcd * mt8 + l / ntl) << 8;
  const int bn = (l % ntl) << 7;

  int row_[2], kk_[2];
#pragma unroll
  for (int j = 0; j < 2; ++j) {
    const int s = j * 8 + (tid >> 6);
    const int r16 = (tid & 63) >> 2;
    const int cb = ((tid & 3) << 4) ^ (((tid >> 5) & 1) << 5);
    row_[j] = (s >> 1) * 16 + r16;
    kk_[j]  = (s & 1) * 32 + (cb >> 1);
  }
  const short* sA0 = A + (size_t)(bm + row_[0]) * K + kk_[0];
  const short* sA1 = A + (size_t)(bm + row_[1]) * K + kk_[1];
  const short* sB0 = W + (size_t)(bn + row_[0]) * K + kk_[0];
  const short* sB1 = W + (size_t)(bn + row_[1]) * K + kk_[1];
  const size_t hstep = (size_t)128 * K;

  const int lofs = fr * 64 + ((fko << 1) ^ (((fr >> 3) & 1) << 5));
  // A reads: wave wm covers rows wm*64 -> local r16 = wm*4 + mi
  const char* ard0 = lsm + wm * 8192 + lofs;
  const char* ard1 = ard0 + 32768;
  // A stage bases
  char* as0 = lsm;
  char* as1 = lsm + 32768;
  // B ring: read ptrs (wn-offset) and stage ptrs
  const char* bur = lsm + 65536 + 0 * 16384 + wn * 8192 + lofs;
  const char* bvr = lsm + 65536 + 1 * 16384 + wn * 8192 + lofs;
  const char* bwr = lsm + 65536 + 2 * 16384 + wn * 8192 + lofs;
  char* bus = lsm + 65536 + 0 * 16384;
  char* bvs = lsm + 65536 + 1 * 16384;
  char* bws = lsm + 65536 + 2 * 16384;

  short8 af[4];
  short8 bfq[4];
  f32x4 acc[4][4] = {};

  const int nk = K >> 6;
  const int nit = nk >> 1;
  const int tmask = nk - 1;

  // prologue: A@0 -> slot0, B@0 -> b0, B@1 -> b1; full drain
  SAK(as0, 0);
  SBK(bus, 0);
  SBK(bvs, 1);
  asm volatile("s_waitcnt vmcnt(0)" ::: "memory");
  __builtin_amdgcn_s_barrier();

  for (int it = 0; it < nit; ++it) {
    const int v  = 2 * it + 1;
    const int t2 = (2 * it + 2) & tmask;
    const int t3 = (2 * it + 3) & tmask;
    PHK(ard0, bur, 0, SAK(as1, v),  NOVM);   // ph1: compute u ks0; stage A@v
    PHK(ard0, bur, 1, SBK(bws, t2), VMC2);   // ph2: u ks1; stage B@u+2; drain A@v
    PHK(ard1, bvr, 0, SAK(as0, t2), NOVM);   // ph3: v ks0; stage A@u+2
    PHK(ard1, bvr, 1, SBK(bus, t3), VMC2);   // ph4: v ks1; stage B@v+2; drain A@u+2,B@u+2
    // rotate B ring: u' -> old w, v' -> old u, w' -> old v
    const char* tr;
    tr = bur; bur = bwr; bwr = bvr; bvr = tr;
    char* ts;
    ts = bus; bus = bws; bws = bvs; bvs = ts;
  }

  asm volatile("s_waitcnt vmcnt(0)" ::: "memory");
  __builtin_amdgcn_s_barrier();

  // epilogue: C/D layout col=lane&15, row=(lane>>4)*4+reg
  const int orow0 = bm + wm * 64 + ((lane >> 4) << 2);
  const int ocol0 = bn + wn * 64 + fr;
#pragma unroll
  for (int mi = 0; mi < 4; ++mi) {
#pragma unroll
    for (int r = 0; r < 4; ++r) {
      const int row = orow0 + mi * 16 + r;
      const size_t base = (size_t)row * N;
#pragma unroll
      for (int ni = 0; ni < 4; ++ni) {
        const int col = ocol0 + ni * 16;
        float v = acc[mi][ni][r];
        if (BIAS) v += bias[col];
        if (GELU) v = gelu_f(v);
        if (QSCALE) v *= (col < 1024 ? 0.18033688f : 1.0f);  // Q *= scale*log2e
        if (RESID) {
          if (RESB16) v += bf2f(((const unsigned short*)resid)[base + col]);
          else        v += ((const float*)resid)[base + col];
        }
        if (OBF16) outB[base + col] = f2bf(v);
        else       outF[base + col] = v;
      }
    }
  }
}

// ---------------- Flash attention, 4 waves x 32 q-rows, mfma 32x32x16 ----------------
__global__ __launch_bounds__(256)
void attn_kernel(const short* __restrict__ qkv, const int* __restrict__ amask,
                 short* __restrict__ out)
{
  __shared__ __align__(16) char lsm[36864];
  char* lsK = lsm;
  char* lsV = lsm + 16384;
  int* lmask = (int*)(lsm + 32768);
  __shared__ int anym;

  const int tid = threadIdx.x;
  const int lane = tid & 63;
  const int w = tid >> 6;
  const int l31 = lane & 31;
  const int hi = lane >> 5;
  const int swz = (l31 & 7) << 4;

  const int bid = blockIdx.x;
  const int swzb = ((bid & 7) << 7) | (bid >> 3);
  const int qt = swzb & 7;
  const int h = (swzb >> 3) & 15;
  const int b = swzb >> 7;
  const size_t rowbase = (size_t)b * SEQ;
  const short* qkvB = qkv + rowbase * 3072 + h * 64;

  const int4 mv = ((const int4*)(amask + b * SEQ))[tid];
  if (tid == 0) anym = 0;
  ((int4*)lmask)[tid] = mv;
  __syncthreads();
  if ((mv.x & mv.y & mv.z & mv.w) == 0) atomicOr(&anym, 1);

  const int q0 = qt * 128 + w * 32;
  const short* qptr = qkvB + (size_t)(q0 + l31) * 3072;
  short8 qf[4];
#pragma unroll
  for (int ks = 0; ks < 4; ++ks)
    qf[ks] = *(const short8*)(qptr + ks * 16 + hi * 8);

  const int krow = tid >> 3;
  const int kcc = (((tid & 7) * 16) ^ ((krow & 7) << 4)) >> 1;
  const short* gK = qkvB + 1024 + kcc;
  char* ldK = lsK + tid * 16;
  const int vr = tid & 63;
  const int vc0 = (tid >> 6) << 3;
  const short* gV = qkvB + 2048 + vc0;

  gload16(gK + (size_t)krow * 3072, ldK);
  gload16(gK + (size_t)(krow + 32) * 3072, ldK + 4096);
  {
    short8 a0 = *(const short8*)(gV + (size_t)vr * 3072);
    short8 a1 = *(const short8*)(gV + (size_t)vr * 3072 + 32);
#pragma unroll
    for (int j = 0; j < 8; ++j) {
      *(short*)(lsV + (vc0 + j) * 128 + ((2 * vr) ^ (j << 4))) = a0[j];
      *(short*)(lsV + (vc0 + 32 + j) * 128 + ((2 * vr) ^ (j << 4))) = a1[j];
    }
  }
  __syncthreads();

  f32x16 oacc[2] = {};
  float psum = 0.f;

  for (int c = 0; c < 16; ++c) {
    const int cur = c & 1;
    const char* lKc = lsK + cur * 8192;
    const char* lVc = lsV + cur * 8192;
    const bool pf = (c < 15);
    short8 vv0, vv1;
    if (pf) {
      const size_t nb_ = (size_t)(c + 1) * 64;
      char* ldKn = ldK + (cur ^ 1) * 8192;
      gload16(gK + (nb_ + krow) * 3072, ldKn);
      gload16(gK + (nb_ + krow + 32) * 3072, ldKn + 4096);
      vv0 = *(const short8*)(gV + (nb_ + vr) * 3072);
      vv1 = *(const short8*)(gV + (nb_ + vr) * 3072 + 32);
    }

    f32x16 pacc[2] = {};
    __builtin_amdgcn_s_setprio(1);
#pragma unroll
    for (int ks = 0; ks < 4; ++ks) {
#pragma unroll
      for (int s = 0; s < 2; ++s) {
        short8 kf = *(const short8*)(lKc + (s * 32 + l31) * 128 +
                                     ((ks * 32 + hi * 16) ^ swz));
        pacc[s] = mfma32(kf, qf[ks], pacc[s]);
      }
    }
    __builtin_amdgcn_s_setprio(0);

    if (pf) {
      char* lVn = lsV + (cur ^ 1) * 8192;
#pragma unroll
      for (int j = 0; j < 8; ++j) {
        *(short*)(lVn + (vc0 + j) * 128 + ((2 * vr) ^ (j << 4))) = vv0[j];
        *(short*)(lVn + (vc0 + 32 + j) * 128 + ((2 * vr) ^ (j << 4))) = vv1[j];
      }
    }

    if (anym) {
      const int kv0 = c * 64;
#pragma unroll
      for (int s = 0; s < 2; ++s)
#pragma unroll
        for (int r = 0; r < 16; ++r) {
          const int kv = kv0 + 32 * s + (r & 3) + 8 * (r >> 2) + 4 * hi;
          if (lmask[kv] == 0) pacc[s][r] = -1e30f;
        }
    }

    float pe[2][16];
#pragma unroll
    for (int s = 0; s < 2; ++s)
#pragma unroll
      for (int r = 0; r < 16; ++r) {
        const float p = __builtin_amdgcn_exp2f(pacc[s][r]);
        pe[s][r] = p;
        psum += p;
      }

    short8 pa[4];
#pragma unroll
    for (int ks = 0; ks < 4; ++ks) {
      const int sh = ks >> 1, kb = (ks & 1) << 3;
      unsigned int aa = cvtpk(pe[sh][kb + 0], pe[sh][kb + 1]);
      unsigned int bb = cvtpk(pe[sh][kb + 4], pe[sh][kb + 5]);
      unsigned int cc = cvtpk(pe[sh][kb + 2], pe[sh][kb + 3]);
      unsigned int dd = cvtpk(pe[sh][kb + 6], pe[sh][kb + 7]);
      asm volatile("v_permlane32_swap_b32 %0, %1" : "+v"(aa), "+v"(bb));
      asm volatile("v_permlane32_swap_b32 %0, %1" : "+v"(cc), "+v"(dd));
      u32x4 t;
      t[0] = aa; t[1] = cc; t[2] = bb; t[3] = dd;
      pa[ks] = __builtin_bit_cast(short8, t);
    }

    __builtin_amdgcn_s_setprio(1);
#pragma unroll
    for (int nb = 0; nb < 2; ++nb)
#pragma unroll
      for (int ks = 0; ks < 4; ++ks) {
        short8 vf = *(const short8*)(lVc + (nb * 32 + l31) * 128 +
                                     ((ks * 32 + hi * 16) ^ swz));
        oacc[nb] = mfma32(pa[ks], vf, oacc[nb]);
      }
    __builtin_amdgcn_s_setprio(0);

    __syncthreads();
  }

  const float lt = psum + __shfl_xor(psum, 32);
  const size_t orow = rowbase + q0;
#pragma unroll
  for (int r = 0; r < 16; ++r) {
    const int q = (r & 3) + 8 * (r >> 2) + 4 * hi;
    const float linv = 1.0f / __shfl(lt, q);
    short* op = out + (orow + q) * DIMC + h * 64 + l31;
    op[0]  = f2bf(oacc[0][r] * linv);
    op[32] = f2bf(oacc[1][r] * linv);
  }
}

// ---------------- orchestration ----------------
extern "C" void kernel_launch(void* const* d_in, const int* in_sizes, int n_in,
                              void* d_out, int out_size, void* d_ws, size_t ws_size,
                              hipStream_t stream)
{
  const float* x      = (const float*)d_in[0];
  const int*   amask  = (const int*)d_in[1];
  const float* ln1_g  = (const float*)d_in[2];
  const float* ln1_b  = (const float*)d_in[3];
  const float* qkv_w  = (const float*)d_in[4];
  const float* proj_w = (const float*)d_in[5];
  const float* proj_b = (const float*)d_in[6];
  const float* ln2_g  = (const float*)d_in[7];
  const float* ln2_b  = (const float*)d_in[8];
  const float* fc1_w  = (const float*)d_in[9];
  const float* fc1_b  = (const float*)d_in[10];
  const float* fc2_w  = (const float*)d_in[11];
  const float* fc2_b  = (const float*)d_in[12];
  float* out = (float*)d_out;

  char* ws = (char*)d_ws;
  short* wqkv  = (short*)(ws);
  short* wproj = (short*)(ws + 6291456);
  short* wfc1  = (short*)(ws + 8388608);
  short* wfc2  = (short*)(ws + 16777216);
  short* x1b   = (short*)(ws + 25165824);   // bf16 residual trunk
  short* hb    = (short*)(ws + 58720256);
  short* qkvo  = (short*)(ws + 75497472);
  short* attno = (short*)(ws + 125829120);
  short* fc1o  = (short*)(ws + 75497472);   // aliases qkvo+attno (dead by then)

  // merged: LN1 (8192 blocks) + all weight converts (12288 blocks)
  prep_kernel<<<NROWS + 12288, 256, 0, stream>>>(
      x, ln1_g, ln1_b, hb, qkv_w, proj_w, fc1_w, fc2_w,
      wqkv, wproj, wfc1, wfc2);

  // QKV: M=8192 N=3072 K=1024 -> 768 blocks (gemm2k), Q cols pre-scaled
  gemm2k<false, false, false, false, true, true><<<768, 512, 0, stream>>>(
      hb, wqkv, nullptr, nullptr, nullptr, qkvo, NROWS, 3 * DIMC, DIMC, 24, 4);

  attn_kernel<<<1024, 256, 0, stream>>>(qkvo, amask, attno);

  // proj + bias + residual(x f32) -> x1b (bf16): 256 blocks (gemm2k)
  gemm2k<true, false, true, false, true, false><<<256, 512, 0, stream>>>(
      attno, wproj, proj_b, x, nullptr, x1b, NROWS, DIMC, DIMC, 8, 4);

  // LN2 on bf16 trunk
  ln_kernel<true><<<NROWS, 256, 0, stream>>>(x1b, ln2_g, ln2_b, hb);

  // FC1 + bias + gelu: N=4096, BN=256 -> 512 blocks (gemm8p control)
  gemm8p<true, true, false, true><<<512, 512, 0, stream>>>(
      hb, wfc1, fc1_b, nullptr, nullptr, fc1o, NROWS, MLPHID, DIMC, 16, 4);

  // FC2 + bias + residual(x1b bf16) -> out (f32): K=4096, 256 blocks (gemm2k)
  gemm2k<true, false, true, true, false, false><<<256, 512, 0, stream>>>(
      fc1o, wfc2, fc2_b, x1b, out, nullptr, NROWS, DIMC, MLPHID, 8, 4);
}

// Round 11
// 320.560 us; speedup vs baseline: 1.0137x; 1.0137x over previous
//
#include <hip/hip_runtime.h>
#include <hip/hip_bf16.h>
#include <stdint.h>
#include <math.h>

#define DIMC 1024
#define SEQ 1024
#define NBATCH 8
#define NHEADS 16
#define HDIM 64
#define MLPHID 4096
#define NROWS (NBATCH*SEQ)

typedef __attribute__((ext_vector_type(8))) short short8;
typedef __attribute__((ext_vector_type(4))) float f32x4;
typedef __attribute__((ext_vector_type(16))) float f32x16;
typedef __attribute__((ext_vector_type(4))) unsigned int u32x4;

__device__ __forceinline__ short f2bf(float f) {
  union { float f; uint32_t u; } x; x.f = f;
  uint32_t r = (x.u + 0x7FFFu + ((x.u >> 16) & 1u)) >> 16;
  return (short)r;
}

__device__ __forceinline__ float bf2f(unsigned short b) {
  union { uint32_t u; float f; } c; c.u = ((uint32_t)b) << 16;
  return c.f;
}

__device__ __forceinline__ unsigned int cvtpk(float lo, float hi_) {
  unsigned int r;
  asm("v_cvt_pk_bf16_f32 %0, %1, %2" : "=v"(r) : "v"(lo), "v"(hi_));
  return r;
}

// tanh-form GELU via hw exp2 + rcp
__device__ __forceinline__ float gelu_f(float v) {
  const float t = v * v;
  const float p = fmaf(t, 0.044715f, 1.0f);
  const float e = __builtin_amdgcn_exp2f(2.3022082f * v * p);
  return v - v * __builtin_amdgcn_rcpf(e + 1.0f);
}

__device__ __forceinline__ f32x4 mfma16(short8 a, short8 b, f32x4 c) {
  return __builtin_amdgcn_mfma_f32_16x16x32_bf16(a, b, c, 0, 0, 0);
}
__device__ __forceinline__ f32x16 mfma32(short8 a, short8 b, f32x16 c) {
  return __builtin_amdgcn_mfma_f32_32x32x16_bf16(a, b, c, 0, 0, 0);
}

__device__ __forceinline__ void gload16(const void* g, void* l) {
  __builtin_amdgcn_global_load_lds(
      (const __attribute__((address_space(1))) uint32_t*)g,
      (__attribute__((address_space(3))) uint32_t*)l, 16, 0, 0);
}

// -------- merged prep: LN1 (blocks 0..8191) + weight converts (8192..20479) --------
__global__ __launch_bounds__(256)
void prep_kernel(const float* __restrict__ x, const float* __restrict__ g,
                 const float* __restrict__ beta, short* __restrict__ hb,
                 const float* __restrict__ w0, const float* __restrict__ w1,
                 const float* __restrict__ w2, const float* __restrict__ w3,
                 short* __restrict__ o0, short* __restrict__ o1,
                 short* __restrict__ o2, short* __restrict__ o3) {
  const int tid = threadIdx.x;
  if (blockIdx.x < NROWS) {
    const int row = blockIdx.x;
    const float4 v = ((const float4*)(x + (size_t)row * DIMC))[tid];
    float s = v.x + v.y + v.z + v.w;
    float q = v.x*v.x + v.y*v.y + v.z*v.z + v.w*v.w;
#pragma unroll
    for (int o = 32; o > 0; o >>= 1) { s += __shfl_down(s, o); q += __shfl_down(q, o); }
    __shared__ float rs[4], rq[4];
    const int lane = tid & 63, w = tid >> 6;
    if (lane == 0) { rs[w] = s; rq[w] = q; }
    __syncthreads();
    s = rs[0] + rs[1] + rs[2] + rs[3];
    q = rq[0] + rq[1] + rq[2] + rq[3];
    const float mean = s * (1.0f / DIMC);
    const float var = q * (1.0f / DIMC) - mean * mean;
    const float rstd = rsqrtf(var + 1e-5f);
    const float4 gv = ((const float4*)g)[tid];
    const float4 bv = ((const float4*)beta)[tid];
    short4 o4;
    o4.x = f2bf((v.x - mean) * rstd * gv.x + bv.x);
    o4.y = f2bf((v.y - mean) * rstd * gv.y + bv.y);
    o4.z = f2bf((v.z - mean) * rstd * gv.z + bv.z);
    o4.w = f2bf((v.w - mean) * rstd * gv.w + bv.w);
    ((short4*)(hb + (size_t)row * DIMC))[tid] = o4;
  } else {
    const int i = (blockIdx.x - NROWS) * 256 + tid;
    const float4* src;
    short4* dst;
    if (i < 786432)       { src = (const float4*)w0 + i;             dst = (short4*)o0 + i; }
    else if (i < 1048576) { src = (const float4*)w1 + (i - 786432);  dst = (short4*)o1 + (i - 786432); }
    else if (i < 2097152) { src = (const float4*)w2 + (i - 1048576); dst = (short4*)o2 + (i - 1048576); }
    else                  { src = (const float4*)w3 + (i - 2097152); dst = (short4*)o3 + (i - 2097152); }
    const float4 v = *src;
    short4 o;
    o.x = f2bf(v.x); o.y = f2bf(v.y); o.z = f2bf(v.z); o.w = f2bf(v.w);
    *dst = o;
  }
}

// ---------------- LayerNorm (row = 1024), bf16 input -> bf16 ----------------
template<bool INBF16>
__global__ __launch_bounds__(256)
void ln_kernel(const void* __restrict__ xin, const float* __restrict__ g,
               const float* __restrict__ beta, short* __restrict__ out) {
  const int row = blockIdx.x;
  const int tid = threadIdx.x;
  float4 v;
  if (INBF16) {
    const short4 vb = ((const short4*)xin)[row * 256 + tid];
    v.x = bf2f((unsigned short)vb.x); v.y = bf2f((unsigned short)vb.y);
    v.z = bf2f((unsigned short)vb.z); v.w = bf2f((unsigned short)vb.w);
  } else {
    v = ((const float4*)xin)[row * 256 + tid];
  }
  float s = v.x + v.y + v.z + v.w;
  float q = v.x*v.x + v.y*v.y + v.z*v.z + v.w*v.w;
#pragma unroll
  for (int o = 32; o > 0; o >>= 1) { s += __shfl_down(s, o); q += __shfl_down(q, o); }
  __shared__ float rs[4], rq[4];
  const int lane = tid & 63, w = tid >> 6;
  if (lane == 0) { rs[w] = s; rq[w] = q; }
  __syncthreads();
  s = rs[0] + rs[1] + rs[2] + rs[3];
  q = rq[0] + rq[1] + rq[2] + rq[3];
  const float mean = s * (1.0f / DIMC);
  const float var = q * (1.0f / DIMC) - mean * mean;
  const float rstd = rsqrtf(var + 1e-5f);
  const float4 gv = ((const float4*)g)[tid];
  const float4 bv = ((const float4*)beta)[tid];
  short4 o4;
  o4.x = f2bf((v.x - mean) * rstd * gv.x + bv.x);
  o4.y = f2bf((v.y - mean) * rstd * gv.y + bv.y);
  o4.z = f2bf((v.z - mean) * rstd * gv.z + bv.z);
  o4.w = f2bf((v.w - mean) * rstd * gv.w + bv.w);
  ((short4*)(out + (size_t)row * DIMC))[tid] = o4;
}

// ======================= GEMM engines =======================
// Region subtile layout: [16r][32k] bf16 (1024B), st_16x32 swizzle (byte col
// ^= ((r16>>3)&1)<<5), staged linearly via global_load_lds from pre-swizzled
// global source; ds_read applies the same involution.
//
// Phase sync: compiler-only fences around each s_barrier keep C++ LDS/global
// ops inside their phase; NO manual lgkmcnt(0)/sched_barrier — the compiler
// emits counted lgkmcnt per MFMA consumer (m97 behavior), letting early MFMAs
// overlap late ds_reads within the phase (removes the m141-style order-pin).

#define NOVM ((void)0)
#define NOST ((void)0)
#define FENCE asm volatile("" ::: "memory")
#define VMC4 asm volatile("s_waitcnt vmcnt(4)" ::: "memory")
#define VMC2 asm volatile("s_waitcnt vmcnt(2)" ::: "memory")

// ---------- gemm8p (FC1): BM=256/BN=256, 8 waves 2Mx4N, LDS 128KB ----------
#define SA(DB, H, T) \
  gload16(sA0 + (H)*hstep + (size_t)(T)*64, stb + ((DB)*4 + (H))*16384); \
  gload16(sA1 + (H)*hstep + (size_t)(T)*64, stb + ((DB)*4 + (H))*16384 + 8192)

#define SB(DB, H, T) \
  gload16(sB0 + (H)*hstep + (size_t)(T)*64, stb + ((DB)*4 + 2 + (H))*16384); \
  gload16(sB1 + (H)*hstep + (size_t)(T)*64, stb + ((DB)*4 + 2 + (H))*16384 + 8192)

#define PH(DB, QA, QB, LDA, LDB, STAGE, VM) \
  do { \
    if (LDB) { \
      _Pragma("unroll") \
      for (int ni = 0; ni < 2; ++ni) { \
        _Pragma("unroll") \
        for (int ks = 0; ks < 2; ++ks) \
          bfv[QB][ni][ks] = *(const short8*)(brd##DB + (((QB)*2 + ni)*2 + ks)*1024); \
      } \
    } \
    if (LDA) { \
      _Pragma("unroll") \
      for (int mi = 0; mi < 4; ++mi) { \
        _Pragma("unroll") \
        for (int ks = 0; ks < 2; ++ks) \
          af[mi][ks] = *(const short8*)(ard##DB + (((QA)*4 + mi)*2 + ks)*1024); \
      } \
    } \
    STAGE; \
    FENCE; \
    __builtin_amdgcn_s_barrier(); \
    FENCE; \
    __builtin_amdgcn_s_setprio(1); \
    _Pragma("unroll") \
    for (int ks = 0; ks < 2; ++ks) { \
      _Pragma("unroll") \
      for (int mi = 0; mi < 4; ++mi) { \
        _Pragma("unroll") \
        for (int ni = 0; ni < 2; ++ni) \
          acc[(QA)*4 + mi][(QB)*2 + ni] = \
            mfma16(af[mi][ks], bfv[QB][ni][ks], acc[(QA)*4 + mi][(QB)*2 + ni]); \
      } \
    } \
    __builtin_amdgcn_s_setprio(0); \
    VM; \
    FENCE; \
    __builtin_amdgcn_s_barrier(); \
    FENCE; \
  } while (0)

template<bool BIAS, bool GELU, bool RESID, bool OBF16>
__global__ __launch_bounds__(512)
void gemm8p(const short* __restrict__ A, const short* __restrict__ W,
            const float* __restrict__ bias, const float* __restrict__ resid,
            float* __restrict__ outF, short* __restrict__ outB,
            int M, int N, int K, int ntl, int mt8)
{
  __shared__ __align__(16) char lsm[131072];
  const int tid = threadIdx.x;
  const int lane = tid & 63;
  const int w = tid >> 6;
  const int wm = w >> 2;
  const int wn = w & 3;
  const int fr = lane & 15;
  const int fko = (lane >> 4) << 3;

  const int bid = blockIdx.x;
  const int xcd = bid & 7, l = bid >> 3;
  const int bm = (xcd * mt8 + l / ntl) << 8;
  const int bn = (l % ntl) << 8;

  int row_[2], kk_[2];
#pragma unroll
  for (int j = 0; j < 2; ++j) {
    const int s = j * 8 + (tid >> 6);
    const int r16 = (tid & 63) >> 2;
    const int cb = ((tid & 3) << 4) ^ (((tid >> 5) & 1) << 5);
    row_[j] = (s >> 1) * 16 + r16;
    kk_[j]  = (s & 1) * 32 + (cb >> 1);
  }
  const short* sA0 = A + (size_t)(bm + row_[0]) * K + kk_[0];
  const short* sA1 = A + (size_t)(bm + row_[1]) * K + kk_[1];
  const short* sB0 = W + (size_t)(bn + row_[0]) * K + kk_[0];
  const short* sB1 = W + (size_t)(bn + row_[1]) * K + kk_[1];
  const size_t hstep = (size_t)128 * K;
  char* stb = lsm + tid * 16;

  const int lofs = fr * 64 + ((fko << 1) ^ (((fr >> 3) & 1) << 5));
  const char* ard0 = lsm + wm * 16384 + lofs;
  const char* brd0 = lsm + 32768 + (wn >> 1) * 16384 + (wn & 1) * 8192 + lofs;
  const char* ard1 = ard0 + 65536;
  const char* brd1 = brd0 + 65536;

  short8 af[4][2];
  short8 bfv[2][2][2];
  f32x4 acc[8][4] = {};

  SA(0, 0, 0); SA(0, 1, 0);
  SB(0, 0, 0); SB(0, 1, 0);
  SB(1, 0, 1); SB(1, 1, 1);
  VMC4;
  __builtin_amdgcn_s_barrier();
  FENCE;

  const int nk = K >> 6;
  const int nit = nk >> 1;
  const int tmask = nk - 1;
  for (int it = 0; it < nit; ++it) {
    const int t1 = 2 * it + 1;
    const int t2 = (2 * it + 2) & tmask;
    const int t3 = (2 * it + 3) & tmask;
    PH(0, 0, 0, 1, 1, SA(1, 0, t1), NOVM);
    PH(0, 0, 1, 0, 1, SA(1, 1, t1), NOVM);
    PH(0, 1, 1, 1, 0, SB(0, 0, t2), NOVM);
    PH(0, 1, 0, 0, 0, SB(0, 1, t2), VMC4);
    PH(1, 0, 0, 1, 1, SA(0, 0, t2), NOVM);
    PH(1, 0, 1, 0, 1, SA(0, 1, t2), NOVM);
    PH(1, 1, 1, 1, 0, SB(1, 0, t3), NOVM);
    PH(1, 1, 0, 0, 0, SB(1, 1, t3), VMC4);
  }

  asm volatile("s_waitcnt vmcnt(0)" ::: "memory");
  __builtin_amdgcn_s_barrier();
  FENCE;

  const int orow0 = bm + wm * 128 + ((lane >> 4) << 2);
  const int ocol0 = bn + wn * 64 + fr;
#pragma unroll
  for (int mi = 0; mi < 8; ++mi) {
#pragma unroll
    for (int r = 0; r < 4; ++r) {
      const int row = orow0 + mi * 16 + r;
      const size_t base = (size_t)row * N;
#pragma unroll
      for (int ni = 0; ni < 4; ++ni) {
        const int col = ocol0 + ni * 16;
        float v = acc[mi][ni][r];
        if (BIAS) v += bias[col];
        if (GELU) v = gelu_f(v);
        if (RESID) v += resid[base + col];
        if (OBF16) outB[base + col] = f2bf(v);
        else       outF[base + col] = v;
      }
    }
  }
}

// ---------- gemm2k: BM=256/BN=128, by-ks phases (16 MFMA + 8 ds_read/phase) ----------
// 8 waves 4Mx2N (64x64/wave), 2 phases/K-tile. LDS 112KB:
//   A slots 2x32KB @0/@32768, B ring 3x16KB @65536.
// Stage: ph1 A@v->slot1, ph2 B@u+2 + vmcnt(2), ph3 A@u+2->slot0,
//        ph4 B@v+2 + vmcnt(2). B reads issued first for early-MFMA overlap.
#define SAK(SLOT, T) \
  gload16(sA0 + (size_t)(T)*64,         (SLOT) + tid*16); \
  gload16(sA1 + (size_t)(T)*64,         (SLOT) + 8192 + tid*16); \
  gload16(sA0 + hstep + (size_t)(T)*64, (SLOT) + 16384 + tid*16); \
  gload16(sA1 + hstep + (size_t)(T)*64, (SLOT) + 24576 + tid*16)

#define SBK(SLOT, T) \
  gload16(sB0 + (size_t)(T)*64, (SLOT) + tid*16); \
  gload16(sB1 + (size_t)(T)*64, (SLOT) + 8192 + tid*16)

#define PHK(ARD, BRD, KS, STAGE, VM) \
  do { \
    _Pragma("unroll") \
    for (int jn = 0; jn < 4; ++jn) \
      bfq[jn] = *(const short8*)((BRD) + (jn*2 + (KS))*1024); \
    _Pragma("unroll") \
    for (int mi = 0; mi < 4; ++mi) \
      af[mi] = *(const short8*)((ARD) + (mi*2 + (KS))*1024); \
    STAGE; \
    FENCE; \
    __builtin_amdgcn_s_barrier(); \
    FENCE; \
    __builtin_amdgcn_s_setprio(1); \
    _Pragma("unroll") \
    for (int mi = 0; mi < 4; ++mi) { \
      _Pragma("unroll") \
      for (int jn = 0; jn < 4; ++jn) \
        acc[mi][jn] = mfma16(af[mi], bfq[jn], acc[mi][jn]); \
    } \
    __builtin_amdgcn_s_setprio(0); \
    VM; \
    FENCE; \
    __builtin_amdgcn_s_barrier(); \
    FENCE; \
  } while (0)

template<bool BIAS, bool GELU, bool RESID, bool RESB16, bool OBF16, bool QSCALE>
__global__ __launch_bounds__(512)
void gemm2k(const short* __restrict__ A, const short* __restrict__ W,
            const float* __restrict__ bias, const void* __restrict__ resid,
            float* __restrict__ outF, short* __restrict__ outB,
            int M, int N, int K, int ntl, int mt8)
{
  __shared__ __align__(16) char lsm[114688];
  const int tid = threadIdx.x;
  const int lane = tid & 63;
  const int w = tid >> 6;
  const int wm = w >> 1;
  const int wn = w & 1;
  const int fr = lane & 15;
  const int fko = (lane >> 4) << 3;

  const int bid = blockIdx.x;
  const int xcd = bid & 7, l = bid >> 3;
  const int bm = (xcd * mt8 + l / ntl) << 8;
  const int bn = (l % ntl) << 7;

  int row_[2], kk_[2];
#pragma unroll
  for (int j = 0; j < 2; ++j) {
    const int s = j * 8 + (tid >> 6);
    const int r16 = (tid & 63) >> 2;
    const int cb = ((tid & 3) << 4) ^ (((tid >> 5) & 1) << 5);
    row_[j] = (s >> 1) * 16 + r16;
    kk_[j]  = (s & 1) * 32 + (cb >> 1);
  }
  const short* sA0 = A + (size_t)(bm + row_[0]) * K + kk_[0];
  const short* sA1 = A + (size_t)(bm + row_[1]) * K + kk_[1];
  const short* sB0 = W + (size_t)(bn + row_[0]) * K + kk_[0];
  const short* sB1 = W + (size_t)(bn + row_[1]) * K + kk_[1];
  const size_t hstep = (size_t)128 * K;

  const int lofs = fr * 64 + ((fko << 1) ^ (((fr >> 3) & 1) << 5));
  const char* ard0 = lsm + wm * 8192 + lofs;
  const char* ard1 = ard0 + 32768;
  char* as0 = lsm;
  char* as1 = lsm + 32768;
  const char* bur = lsm + 65536 + 0 * 16384 + wn * 8192 + lofs;
  const char* bvr = lsm + 65536 + 1 * 16384 + wn * 8192 + lofs;
  const char* bwr = lsm + 65536 + 2 * 16384 + wn * 8192 + lofs;
  char* bus = lsm + 65536 + 0 * 16384;
  char* bvs = lsm + 65536 + 1 * 16384;
  char* bws = lsm + 65536 + 2 * 16384;

  short8 af[4];
  short8 bfq[4];
  f32x4 acc[4][4] = {};

  const int nk = K >> 6;
  const int nit = nk >> 1;
  const int tmask = nk - 1;

  SAK(as0, 0);
  SBK(bus, 0);
  SBK(bvs, 1);
  asm volatile("s_waitcnt vmcnt(0)" ::: "memory");
  __builtin_amdgcn_s_barrier();
  FENCE;

  for (int it = 0; it < nit; ++it) {
    const int v  = 2 * it + 1;
    const int t2 = (2 * it + 2) & tmask;
    const int t3 = (2 * it + 3) & tmask;
    PHK(ard0, bur, 0, SAK(as1, v),  NOVM);
    PHK(ard0, bur, 1, SBK(bws, t2), VMC2);
    PHK(ard1, bvr, 0, SAK(as0, t2), NOVM);
    PHK(ard1, bvr, 1, SBK(bus, t3), VMC2);
    const char* tr;
    tr = bur; bur = bwr; bwr = bvr; bvr = tr;
    char* ts;
    ts = bus; bus = bws; bws = bvs; bvs = ts;
  }

  asm volatile("s_waitcnt vmcnt(0)" ::: "memory");
  __builtin_amdgcn_s_barrier();
  FENCE;

  const int orow0 = bm + wm * 64 + ((lane >> 4) << 2);
  const int ocol0 = bn + wn * 64 + fr;
#pragma unroll
  for (int mi = 0; mi < 4; ++mi) {
#pragma unroll
    for (int r = 0; r < 4; ++r) {
      const int row = orow0 + mi * 16 + r;
      const size_t base = (size_t)row * N;
#pragma unroll
      for (int ni = 0; ni < 4; ++ni) {
        const int col = ocol0 + ni * 16;
        float v = acc[mi][ni][r];
        if (BIAS) v += bias[col];
        if (GELU) v = gelu_f(v);
        if (QSCALE) v *= (col < 1024 ? 0.18033688f : 1.0f);  // Q *= scale*log2e
        if (RESID) {
          if (RESB16) v += bf2f(((const unsigned short*)resid)[base + col]);
          else        v += ((const float*)resid)[base + col];
        }
        if (OBF16) outB[base + col] = f2bf(v);
        else       outF[base + col] = v;
      }
    }
  }
}

// ---------------- Flash attention, 4 waves x 32 q-rows, mfma 32x32x16 ----------------
__global__ __launch_bounds__(256)
void attn_kernel(const short* __restrict__ qkv, const int* __restrict__ amask,
                 short* __restrict__ out)
{
  __shared__ __align__(16) char lsm[36864];
  char* lsK = lsm;
  char* lsV = lsm + 16384;
  int* lmask = (int*)(lsm + 32768);
  __shared__ int anym;

  const int tid = threadIdx.x;
  const int lane = tid & 63;
  const int w = tid >> 6;
  const int l31 = lane & 31;
  const int hi = lane >> 5;
  const int swz = (l31 & 7) << 4;

  const int bid = blockIdx.x;
  const int swzb = ((bid & 7) << 7) | (bid >> 3);
  const int qt = swzb & 7;
  const int h = (swzb >> 3) & 15;
  const int b = swzb >> 7;
  const size_t rowbase = (size_t)b * SEQ;
  const short* qkvB = qkv + rowbase * 3072 + h * 64;

  const int4 mv = ((const int4*)(amask + b * SEQ))[tid];
  if (tid == 0) anym = 0;
  ((int4*)lmask)[tid] = mv;
  __syncthreads();
  if ((mv.x & mv.y & mv.z & mv.w) == 0) atomicOr(&anym, 1);

  const int q0 = qt * 128 + w * 32;
  const short* qptr = qkvB + (size_t)(q0 + l31) * 3072;
  short8 qf[4];
#pragma unroll
  for (int ks = 0; ks < 4; ++ks)
    qf[ks] = *(const short8*)(qptr + ks * 16 + hi * 8);

  const int krow = tid >> 3;
  const int kcc = (((tid & 7) * 16) ^ ((krow & 7) << 4)) >> 1;
  const short* gK = qkvB + 1024 + kcc;
  char* ldK = lsK + tid * 16;
  const int vr = tid & 63;
  const int vc0 = (tid >> 6) << 3;
  const short* gV = qkvB + 2048 + vc0;

  gload16(gK + (size_t)krow * 3072, ldK);
  gload16(gK + (size_t)(krow + 32) * 3072, ldK + 4096);
  {
    short8 a0 = *(const short8*)(gV + (size_t)vr * 3072);
    short8 a1 = *(const short8*)(gV + (size_t)vr * 3072 + 32);
#pragma unroll
    for (int j = 0; j < 8; ++j) {
      *(short*)(lsV + (vc0 + j) * 128 + ((2 * vr) ^ (j << 4))) = a0[j];
      *(short*)(lsV + (vc0 + 32 + j) * 128 + ((2 * vr) ^ (j << 4))) = a1[j];
    }
  }
  __syncthreads();

  f32x16 oacc[2] = {};
  float psum = 0.f;

  for (int c = 0; c < 16; ++c) {
    const int cur = c & 1;
    const char* lKc = lsK + cur * 8192;
    const char* lVc = lsV + cur * 8192;
    const bool pf = (c < 15);
    short8 vv0, vv1;
    if (pf) {
      const size_t nb_ = (size_t)(c + 1) * 64;
      char* ldKn = ldK + (cur ^ 1) * 8192;
      gload16(gK + (nb_ + krow) * 3072, ldKn);
      gload16(gK + (nb_ + krow + 32) * 3072, ldKn + 4096);
      vv0 = *(const short8*)(gV + (nb_ + vr) * 3072);
      vv1 = *(const short8*)(gV + (nb_ + vr) * 3072 + 32);
    }

    f32x16 pacc[2] = {};
    __builtin_amdgcn_s_setprio(1);
#pragma unroll
    for (int ks = 0; ks < 4; ++ks) {
#pragma unroll
      for (int s = 0; s < 2; ++s) {
        short8 kf = *(const short8*)(lKc + (s * 32 + l31) * 128 +
                                     ((ks * 32 + hi * 16) ^ swz));
        pacc[s] = mfma32(kf, qf[ks], pacc[s]);
      }
    }
    __builtin_amdgcn_s_setprio(0);

    if (pf) {
      char* lVn = lsV + (cur ^ 1) * 8192;
#pragma unroll
      for (int j = 0; j < 8; ++j) {
        *(short*)(lVn + (vc0 + j) * 128 + ((2 * vr) ^ (j << 4))) = vv0[j];
        *(short*)(lVn + (vc0 + 32 + j) * 128 + ((2 * vr) ^ (j << 4))) = vv1[j];
      }
    }

    if (anym) {
      const int kv0 = c * 64;
#pragma unroll
      for (int s = 0; s < 2; ++s)
#pragma unroll
        for (int r = 0; r < 16; ++r) {
          const int kv = kv0 + 32 * s + (r & 3) + 8 * (r >> 2) + 4 * hi;
          if (lmask[kv] == 0) pacc[s][r] = -1e30f;
        }
    }

    float pe[2][16];
#pragma unroll
    for (int s = 0; s < 2; ++s)
#pragma unroll
      for (int r = 0; r < 16; ++r) {
        const float p = __builtin_amdgcn_exp2f(pacc[s][r]);
        pe[s][r] = p;
        psum += p;
      }

    short8 pa[4];
#pragma unroll
    for (int ks = 0; ks < 4; ++ks) {
      const int sh = ks >> 1, kb = (ks & 1) << 3;
      unsigned int aa = cvtpk(pe[sh][kb + 0], pe[sh][kb + 1]);
      unsigned int bb = cvtpk(pe[sh][kb + 4], pe[sh][kb + 5]);
      unsigned int cc = cvtpk(pe[sh][kb + 2], pe[sh][kb + 3]);
      unsigned int dd = cvtpk(pe[sh][kb + 6], pe[sh][kb + 7]);
      asm volatile("v_permlane32_swap_b32 %0, %1" : "+v"(aa), "+v"(bb));
      asm volatile("v_permlane32_swap_b32 %0, %1" : "+v"(cc), "+v"(dd));
      u32x4 t;
      t[0] = aa; t[1] = cc; t[2] = bb; t[3] = dd;
      pa[ks] = __builtin_bit_cast(short8, t);
    }

    __builtin_amdgcn_s_setprio(1);
#pragma unroll
    for (int nb = 0; nb < 2; ++nb)
#pragma unroll
      for (int ks = 0; ks < 4; ++ks) {
        short8 vf = *(const short8*)(lVc + (nb * 32 + l31) * 128 +
                                     ((ks * 32 + hi * 16) ^ swz));
        oacc[nb] = mfma32(pa[ks], vf, oacc[nb]);
      }
    __builtin_amdgcn_s_setprio(0);

    __syncthreads();
  }

  const float lt = psum + __shfl_xor(psum, 32);
  const size_t orow = rowbase + q0;
#pragma unroll
  for (int r = 0; r < 16; ++r) {
    const int q = (r & 3) + 8 * (r >> 2) + 4 * hi;
    const float linv = 1.0f / __shfl(lt, q);
    short* op = out + (orow + q) * DIMC + h * 64 + l31;
    op[0]  = f2bf(oacc[0][r] * linv);
    op[32] = f2bf(oacc[1][r] * linv);
  }
}

// ---------------- orchestration ----------------
extern "C" void kernel_launch(void* const* d_in, const int* in_sizes, int n_in,
                              void* d_out, int out_size, void* d_ws, size_t ws_size,
                              hipStream_t stream)
{
  const float* x      = (const float*)d_in[0];
  const int*   amask  = (const int*)d_in[1];
  const float* ln1_g  = (const float*)d_in[2];
  const float* ln1_b  = (const float*)d_in[3];
  const float* qkv_w  = (const float*)d_in[4];
  const float* proj_w = (const float*)d_in[5];
  const float* proj_b = (const float*)d_in[6];
  const float* ln2_g  = (const float*)d_in[7];
  const float* ln2_b  = (const float*)d_in[8];
  const float* fc1_w  = (const float*)d_in[9];
  const float* fc1_b  = (const float*)d_in[10];
  const float* fc2_w  = (const float*)d_in[11];
  const float* fc2_b  = (const float*)d_in[12];
  float* out = (float*)d_out;

  char* ws = (char*)d_ws;
  short* wqkv  = (short*)(ws);
  short* wproj = (short*)(ws + 6291456);
  short* wfc1  = (short*)(ws + 8388608);
  short* wfc2  = (short*)(ws + 16777216);
  short* x1b   = (short*)(ws + 25165824);   // bf16 residual trunk
  short* hb    = (short*)(ws + 58720256);
  short* qkvo  = (short*)(ws + 75497472);
  short* attno = (short*)(ws + 125829120);
  short* fc1o  = (short*)(ws + 75497472);   // aliases qkvo+attno (dead by then)

  // merged: LN1 (8192 blocks) + all weight converts (12288 blocks)
  prep_kernel<<<NROWS + 12288, 256, 0, stream>>>(
      x, ln1_g, ln1_b, hb, qkv_w, proj_w, fc1_w, fc2_w,
      wqkv, wproj, wfc1, wfc2);

  // QKV: M=8192 N=3072 K=1024 -> 768 blocks (gemm2k), Q cols pre-scaled
  gemm2k<false, false, false, false, true, true><<<768, 512, 0, stream>>>(
      hb, wqkv, nullptr, nullptr, nullptr, qkvo, NROWS, 3 * DIMC, DIMC, 24, 4);

  attn_kernel<<<1024, 256, 0, stream>>>(qkvo, amask, attno);

  // proj + bias + residual(x f32) -> x1b (bf16): 256 blocks (gemm2k)
  gemm2k<true, false, true, false, true, false><<<256, 512, 0, stream>>>(
      attno, wproj, proj_b, x, nullptr, x1b, NROWS, DIMC, DIMC, 8, 4);

  // LN2 on bf16 trunk
  ln_kernel<true><<<NROWS, 256, 0, stream>>>(x1b, ln2_g, ln2_b, hb);

  // FC1 + bias + gelu: N=4096, BN=256 -> 512 blocks (gemm8p)
  gemm8p<true, true, false, true><<<512, 512, 0, stream>>>(
      hb, wfc1, fc1_b, nullptr, nullptr, fc1o, NROWS, MLPHID, DIMC, 16, 4);

  // FC2 + bias + residual(x1b bf16) -> out (f32): K=4096, 256 blocks (gemm2k)
  gemm2k<true, false, true, true, false, false><<<256, 512, 0, stream>>>(
      fc1o, wfc2, fc2_b, x1b, out, nullptr, NROWS, DIMC, MLPHID, 8, 4);
}

// Round 12
// 306.552 us; speedup vs baseline: 1.0600x; 1.0457x over previous
//
#include <hip/hip_runtime.h>
#include <hip/hip_bf16.h>
#include <stdint.h>
#include <math.h>

#define DIMC 1024
#define SEQ 1024
#define NBATCH 8
#define NHEADS 16
#define HDIM 64
#define MLPHID 4096
#define NROWS (NBATCH*SEQ)

typedef __attribute__((ext_vector_type(8))) short short8;
typedef __attribute__((ext_vector_type(4))) float f32x4;
typedef __attribute__((ext_vector_type(16))) float f32x16;
typedef __attribute__((ext_vector_type(4))) unsigned int u32x4;

__device__ __forceinline__ short f2bf(float f) {
  union { float f; uint32_t u; } x; x.f = f;
  uint32_t r = (x.u + 0x7FFFu + ((x.u >> 16) & 1u)) >> 16;
  return (short)r;
}

__device__ __forceinline__ float bf2f(unsigned short b) {
  union { uint32_t u; float f; } c; c.u = ((uint32_t)b) << 16;
  return c.f;
}

__device__ __forceinline__ unsigned int cvtpk(float lo, float hi_) {
  unsigned int r;
  asm("v_cvt_pk_bf16_f32 %0, %1, %2" : "=v"(r) : "v"(lo), "v"(hi_));
  return r;
}

// tanh-form GELU via hw exp2 + rcp
__device__ __forceinline__ float gelu_f(float v) {
  const float t = v * v;
  const float p = fmaf(t, 0.044715f, 1.0f);
  const float e = __builtin_amdgcn_exp2f(2.3022082f * v * p);
  return v - v * __builtin_amdgcn_rcpf(e + 1.0f);
}

__device__ __forceinline__ f32x4 mfma16(short8 a, short8 b, f32x4 c) {
  return __builtin_amdgcn_mfma_f32_16x16x32_bf16(a, b, c, 0, 0, 0);
}
__device__ __forceinline__ f32x16 mfma32(short8 a, short8 b, f32x16 c) {
  return __builtin_amdgcn_mfma_f32_32x32x16_bf16(a, b, c, 0, 0, 0);
}

__device__ __forceinline__ void gload16(const void* g, void* l) {
  __builtin_amdgcn_global_load_lds(
      (const __attribute__((address_space(1))) uint32_t*)g,
      (__attribute__((address_space(3))) uint32_t*)l, 16, 0, 0);
}

// -------- merged prep: LN1 (blocks 0..8191) + weight converts (8192..20479) --------
__global__ __launch_bounds__(256)
void prep_kernel(const float* __restrict__ x, const float* __restrict__ g,
                 const float* __restrict__ beta, short* __restrict__ hb,
                 const float* __restrict__ w0, const float* __restrict__ w1,
                 const float* __restrict__ w2, const float* __restrict__ w3,
                 short* __restrict__ o0, short* __restrict__ o1,
                 short* __restrict__ o2, short* __restrict__ o3) {
  const int tid = threadIdx.x;
  if (blockIdx.x < NROWS) {
    const int row = blockIdx.x;
    const float4 v = ((const float4*)(x + (size_t)row * DIMC))[tid];
    float s = v.x + v.y + v.z + v.w;
    float q = v.x*v.x + v.y*v.y + v.z*v.z + v.w*v.w;
#pragma unroll
    for (int o = 32; o > 0; o >>= 1) { s += __shfl_down(s, o); q += __shfl_down(q, o); }
    __shared__ float rs[4], rq[4];
    const int lane = tid & 63, w = tid >> 6;
    if (lane == 0) { rs[w] = s; rq[w] = q; }
    __syncthreads();
    s = rs[0] + rs[1] + rs[2] + rs[3];
    q = rq[0] + rq[1] + rq[2] + rq[3];
    const float mean = s * (1.0f / DIMC);
    const float var = q * (1.0f / DIMC) - mean * mean;
    const float rstd = rsqrtf(var + 1e-5f);
    const float4 gv = ((const float4*)g)[tid];
    const float4 bv = ((const float4*)beta)[tid];
    short4 o4;
    o4.x = f2bf((v.x - mean) * rstd * gv.x + bv.x);
    o4.y = f2bf((v.y - mean) * rstd * gv.y + bv.y);
    o4.z = f2bf((v.z - mean) * rstd * gv.z + bv.z);
    o4.w = f2bf((v.w - mean) * rstd * gv.w + bv.w);
    ((short4*)(hb + (size_t)row * DIMC))[tid] = o4;
  } else {
    const int i = (blockIdx.x - NROWS) * 256 + tid;
    const float4* src;
    short4* dst;
    if (i < 786432)       { src = (const float4*)w0 + i;             dst = (short4*)o0 + i; }
    else if (i < 1048576) { src = (const float4*)w1 + (i - 786432);  dst = (short4*)o1 + (i - 786432); }
    else if (i < 2097152) { src = (const float4*)w2 + (i - 1048576); dst = (short4*)o2 + (i - 1048576); }
    else                  { src = (const float4*)w3 + (i - 2097152); dst = (short4*)o3 + (i - 2097152); }
    const float4 v = *src;
    short4 o;
    o.x = f2bf(v.x); o.y = f2bf(v.y); o.z = f2bf(v.z); o.w = f2bf(v.w);
    *dst = o;
  }
}

// ---------------- LayerNorm (row = 1024), bf16 input -> bf16 ----------------
template<bool INBF16>
__global__ __launch_bounds__(256)
void ln_kernel(const void* __restrict__ xin, const float* __restrict__ g,
               const float* __restrict__ beta, short* __restrict__ out) {
  const int row = blockIdx.x;
  const int tid = threadIdx.x;
  float4 v;
  if (INBF16) {
    const short4 vb = ((const short4*)xin)[row * 256 + tid];
    v.x = bf2f((unsigned short)vb.x); v.y = bf2f((unsigned short)vb.y);
    v.z = bf2f((unsigned short)vb.z); v.w = bf2f((unsigned short)vb.w);
  } else {
    v = ((const float4*)xin)[row * 256 + tid];
  }
  float s = v.x + v.y + v.z + v.w;
  float q = v.x*v.x + v.y*v.y + v.z*v.z + v.w*v.w;
#pragma unroll
  for (int o = 32; o > 0; o >>= 1) { s += __shfl_down(s, o); q += __shfl_down(q, o); }
  __shared__ float rs[4], rq[4];
  const int lane = tid & 63, w = tid >> 6;
  if (lane == 0) { rs[w] = s; rq[w] = q; }
  __syncthreads();
  s = rs[0] + rs[1] + rs[2] + rs[3];
  q = rq[0] + rq[1] + rq[2] + rq[3];
  const float mean = s * (1.0f / DIMC);
  const float var = q * (1.0f / DIMC) - mean * mean;
  const float rstd = rsqrtf(var + 1e-5f);
  const float4 gv = ((const float4*)g)[tid];
  const float4 bv = ((const float4*)beta)[tid];
  short4 o4;
  o4.x = f2bf((v.x - mean) * rstd * gv.x + bv.x);
  o4.y = f2bf((v.y - mean) * rstd * gv.y + bv.y);
  o4.z = f2bf((v.z - mean) * rstd * gv.z + bv.z);
  o4.w = f2bf((v.w - mean) * rstd * gv.w + bv.w);
  ((short4*)(out + (size_t)row * DIMC))[tid] = o4;
}

// ======================= GEMM engines (round-11, unchanged) =======================
#define NOVM ((void)0)
#define NOST ((void)0)
#define FENCE asm volatile("" ::: "memory")
#define VMC4 asm volatile("s_waitcnt vmcnt(4)" ::: "memory")
#define VMC2 asm volatile("s_waitcnt vmcnt(2)" ::: "memory")

// ---------- gemm8p (FC1): BM=256/BN=256, 8 waves 2Mx4N, LDS 128KB ----------
#define SA(DB, H, T) \
  gload16(sA0 + (H)*hstep + (size_t)(T)*64, stb + ((DB)*4 + (H))*16384); \
  gload16(sA1 + (H)*hstep + (size_t)(T)*64, stb + ((DB)*4 + (H))*16384 + 8192)

#define SB(DB, H, T) \
  gload16(sB0 + (H)*hstep + (size_t)(T)*64, stb + ((DB)*4 + 2 + (H))*16384); \
  gload16(sB1 + (H)*hstep + (size_t)(T)*64, stb + ((DB)*4 + 2 + (H))*16384 + 8192)

#define PH(DB, QA, QB, LDA, LDB, STAGE, VM) \
  do { \
    if (LDB) { \
      _Pragma("unroll") \
      for (int ni = 0; ni < 2; ++ni) { \
        _Pragma("unroll") \
        for (int ks = 0; ks < 2; ++ks) \
          bfv[QB][ni][ks] = *(const short8*)(brd##DB + (((QB)*2 + ni)*2 + ks)*1024); \
      } \
    } \
    if (LDA) { \
      _Pragma("unroll") \
      for (int mi = 0; mi < 4; ++mi) { \
        _Pragma("unroll") \
        for (int ks = 0; ks < 2; ++ks) \
          af[mi][ks] = *(const short8*)(ard##DB + (((QA)*4 + mi)*2 + ks)*1024); \
      } \
    } \
    STAGE; \
    FENCE; \
    __builtin_amdgcn_s_barrier(); \
    FENCE; \
    __builtin_amdgcn_s_setprio(1); \
    _Pragma("unroll") \
    for (int ks = 0; ks < 2; ++ks) { \
      _Pragma("unroll") \
      for (int mi = 0; mi < 4; ++mi) { \
        _Pragma("unroll") \
        for (int ni = 0; ni < 2; ++ni) \
          acc[(QA)*4 + mi][(QB)*2 + ni] = \
            mfma16(af[mi][ks], bfv[QB][ni][ks], acc[(QA)*4 + mi][(QB)*2 + ni]); \
      } \
    } \
    __builtin_amdgcn_s_setprio(0); \
    VM; \
    FENCE; \
    __builtin_amdgcn_s_barrier(); \
    FENCE; \
  } while (0)

template<bool BIAS, bool GELU, bool RESID, bool OBF16>
__global__ __launch_bounds__(512)
void gemm8p(const short* __restrict__ A, const short* __restrict__ W,
            const float* __restrict__ bias, const float* __restrict__ resid,
            float* __restrict__ outF, short* __restrict__ outB,
            int M, int N, int K, int ntl, int mt8)
{
  __shared__ __align__(16) char lsm[131072];
  const int tid = threadIdx.x;
  const int lane = tid & 63;
  const int w = tid >> 6;
  const int wm = w >> 2;
  const int wn = w & 3;
  const int fr = lane & 15;
  const int fko = (lane >> 4) << 3;

  const int bid = blockIdx.x;
  const int xcd = bid & 7, l = bid >> 3;
  const int bm = (xcd * mt8 + l / ntl) << 8;
  const int bn = (l % ntl) << 8;

  int row_[2], kk_[2];
#pragma unroll
  for (int j = 0; j < 2; ++j) {
    const int s = j * 8 + (tid >> 6);
    const int r16 = (tid & 63) >> 2;
    const int cb = ((tid & 3) << 4) ^ (((tid >> 5) & 1) << 5);
    row_[j] = (s >> 1) * 16 + r16;
    kk_[j]  = (s & 1) * 32 + (cb >> 1);
  }
  const short* sA0 = A + (size_t)(bm + row_[0]) * K + kk_[0];
  const short* sA1 = A + (size_t)(bm + row_[1]) * K + kk_[1];
  const short* sB0 = W + (size_t)(bn + row_[0]) * K + kk_[0];
  const short* sB1 = W + (size_t)(bn + row_[1]) * K + kk_[1];
  const size_t hstep = (size_t)128 * K;
  char* stb = lsm + tid * 16;

  const int lofs = fr * 64 + ((fko << 1) ^ (((fr >> 3) & 1) << 5));
  const char* ard0 = lsm + wm * 16384 + lofs;
  const char* brd0 = lsm + 32768 + (wn >> 1) * 16384 + (wn & 1) * 8192 + lofs;
  const char* ard1 = ard0 + 65536;
  const char* brd1 = brd0 + 65536;

  short8 af[4][2];
  short8 bfv[2][2][2];
  f32x4 acc[8][4] = {};

  SA(0, 0, 0); SA(0, 1, 0);
  SB(0, 0, 0); SB(0, 1, 0);
  SB(1, 0, 1); SB(1, 1, 1);
  VMC4;
  __builtin_amdgcn_s_barrier();
  FENCE;

  const int nk = K >> 6;
  const int nit = nk >> 1;
  const int tmask = nk - 1;
  for (int it = 0; it < nit; ++it) {
    const int t1 = 2 * it + 1;
    const int t2 = (2 * it + 2) & tmask;
    const int t3 = (2 * it + 3) & tmask;
    PH(0, 0, 0, 1, 1, SA(1, 0, t1), NOVM);
    PH(0, 0, 1, 0, 1, SA(1, 1, t1), NOVM);
    PH(0, 1, 1, 1, 0, SB(0, 0, t2), NOVM);
    PH(0, 1, 0, 0, 0, SB(0, 1, t2), VMC4);
    PH(1, 0, 0, 1, 1, SA(0, 0, t2), NOVM);
    PH(1, 0, 1, 0, 1, SA(0, 1, t2), NOVM);
    PH(1, 1, 1, 1, 0, SB(1, 0, t3), NOVM);
    PH(1, 1, 0, 0, 0, SB(1, 1, t3), VMC4);
  }

  asm volatile("s_waitcnt vmcnt(0)" ::: "memory");
  __builtin_amdgcn_s_barrier();
  FENCE;

  const int orow0 = bm + wm * 128 + ((lane >> 4) << 2);
  const int ocol0 = bn + wn * 64 + fr;
#pragma unroll
  for (int mi = 0; mi < 8; ++mi) {
#pragma unroll
    for (int r = 0; r < 4; ++r) {
      const int row = orow0 + mi * 16 + r;
      const size_t base = (size_t)row * N;
#pragma unroll
      for (int ni = 0; ni < 4; ++ni) {
        const int col = ocol0 + ni * 16;
        float v = acc[mi][ni][r];
        if (BIAS) v += bias[col];
        if (GELU) v = gelu_f(v);
        if (RESID) v += resid[base + col];
        if (OBF16) outB[base + col] = f2bf(v);
        else       outF[base + col] = v;
      }
    }
  }
}

// ---------- gemm2k: BM=256/BN=128, by-ks phases (16 MFMA + 8 ds_read/phase) ----------
#define SAK(SLOT, T) \
  gload16(sA0 + (size_t)(T)*64,         (SLOT) + tid*16); \
  gload16(sA1 + (size_t)(T)*64,         (SLOT) + 8192 + tid*16); \
  gload16(sA0 + hstep + (size_t)(T)*64, (SLOT) + 16384 + tid*16); \
  gload16(sA1 + hstep + (size_t)(T)*64, (SLOT) + 24576 + tid*16)

#define SBK(SLOT, T) \
  gload16(sB0 + (size_t)(T)*64, (SLOT) + tid*16); \
  gload16(sB1 + (size_t)(T)*64, (SLOT) + 8192 + tid*16)

#define PHK(ARD, BRD, KS, STAGE, VM) \
  do { \
    _Pragma("unroll") \
    for (int jn = 0; jn < 4; ++jn) \
      bfq[jn] = *(const short8*)((BRD) + (jn*2 + (KS))*1024); \
    _Pragma("unroll") \
    for (int mi = 0; mi < 4; ++mi) \
      af[mi] = *(const short8*)((ARD) + (mi*2 + (KS))*1024); \
    STAGE; \
    FENCE; \
    __builtin_amdgcn_s_barrier(); \
    FENCE; \
    __builtin_amdgcn_s_setprio(1); \
    _Pragma("unroll") \
    for (int mi = 0; mi < 4; ++mi) { \
      _Pragma("unroll") \
      for (int jn = 0; jn < 4; ++jn) \
        acc[mi][jn] = mfma16(af[mi], bfq[jn], acc[mi][jn]); \
    } \
    __builtin_amdgcn_s_setprio(0); \
    VM; \
    FENCE; \
    __builtin_amdgcn_s_barrier(); \
    FENCE; \
  } while (0)

template<bool BIAS, bool GELU, bool RESID, bool RESB16, bool OBF16, bool QSCALE>
__global__ __launch_bounds__(512)
void gemm2k(const short* __restrict__ A, const short* __restrict__ W,
            const float* __restrict__ bias, const void* __restrict__ resid,
            float* __restrict__ outF, short* __restrict__ outB,
            int M, int N, int K, int ntl, int mt8)
{
  __shared__ __align__(16) char lsm[114688];
  const int tid = threadIdx.x;
  const int lane = tid & 63;
  const int w = tid >> 6;
  const int wm = w >> 1;
  const int wn = w & 1;
  const int fr = lane & 15;
  const int fko = (lane >> 4) << 3;

  const int bid = blockIdx.x;
  const int xcd = bid & 7, l = bid >> 3;
  const int bm = (xcd * mt8 + l / ntl) << 8;
  const int bn = (l % ntl) << 7;

  int row_[2], kk_[2];
#pragma unroll
  for (int j = 0; j < 2; ++j) {
    const int s = j * 8 + (tid >> 6);
    const int r16 = (tid & 63) >> 2;
    const int cb = ((tid & 3) << 4) ^ (((tid >> 5) & 1) << 5);
    row_[j] = (s >> 1) * 16 + r16;
    kk_[j]  = (s & 1) * 32 + (cb >> 1);
  }
  const short* sA0 = A + (size_t)(bm + row_[0]) * K + kk_[0];
  const short* sA1 = A + (size_t)(bm + row_[1]) * K + kk_[1];
  const short* sB0 = W + (size_t)(bn + row_[0]) * K + kk_[0];
  const short* sB1 = W + (size_t)(bn + row_[1]) * K + kk_[1];
  const size_t hstep = (size_t)128 * K;

  const int lofs = fr * 64 + ((fko << 1) ^ (((fr >> 3) & 1) << 5));
  const char* ard0 = lsm + wm * 8192 + lofs;
  const char* ard1 = ard0 + 32768;
  char* as0 = lsm;
  char* as1 = lsm + 32768;
  const char* bur = lsm + 65536 + 0 * 16384 + wn * 8192 + lofs;
  const char* bvr = lsm + 65536 + 1 * 16384 + wn * 8192 + lofs;
  const char* bwr = lsm + 65536 + 2 * 16384 + wn * 8192 + lofs;
  char* bus = lsm + 65536 + 0 * 16384;
  char* bvs = lsm + 65536 + 1 * 16384;
  char* bws = lsm + 65536 + 2 * 16384;

  short8 af[4];
  short8 bfq[4];
  f32x4 acc[4][4] = {};

  const int nk = K >> 6;
  const int nit = nk >> 1;
  const int tmask = nk - 1;

  SAK(as0, 0);
  SBK(bus, 0);
  SBK(bvs, 1);
  asm volatile("s_waitcnt vmcnt(0)" ::: "memory");
  __builtin_amdgcn_s_barrier();
  FENCE;

  for (int it = 0; it < nit; ++it) {
    const int v  = 2 * it + 1;
    const int t2 = (2 * it + 2) & tmask;
    const int t3 = (2 * it + 3) & tmask;
    PHK(ard0, bur, 0, SAK(as1, v),  NOVM);
    PHK(ard0, bur, 1, SBK(bws, t2), VMC2);
    PHK(ard1, bvr, 0, SAK(as0, t2), NOVM);
    PHK(ard1, bvr, 1, SBK(bus, t3), VMC2);
    const char* tr;
    tr = bur; bur = bwr; bwr = bvr; bvr = tr;
    char* ts;
    ts = bus; bus = bws; bws = bvs; bvs = ts;
  }

  asm volatile("s_waitcnt vmcnt(0)" ::: "memory");
  __builtin_amdgcn_s_barrier();
  FENCE;

  const int orow0 = bm + wm * 64 + ((lane >> 4) << 2);
  const int ocol0 = bn + wn * 64 + fr;
#pragma unroll
  for (int mi = 0; mi < 4; ++mi) {
#pragma unroll
    for (int r = 0; r < 4; ++r) {
      const int row = orow0 + mi * 16 + r;
      const size_t base = (size_t)row * N;
#pragma unroll
      for (int ni = 0; ni < 4; ++ni) {
        const int col = ocol0 + ni * 16;
        float v = acc[mi][ni][r];
        if (BIAS) v += bias[col];
        if (GELU) v = gelu_f(v);
        if (QSCALE) v *= (col < 1024 ? 0.18033688f : 1.0f);  // Q *= scale*log2e
        if (RESID) {
          if (RESB16) v += bf2f(((const unsigned short*)resid)[base + col]);
          else        v += ((const float*)resid)[base + col];
        }
        if (OBF16) outB[base + col] = f2bf(v);
        else       outF[base + col] = v;
      }
    }
  }
}

// ---------------- Flash attention, 8 waves x 32 q-rows (256 q/block) ----------------
// Halved per-thread staging vs 4-wave version: 1 K-gload + 8 V-scatter stores
// per chunk per thread. Same per-wave MFMA/softmax structure; 2 blk/CU x 8 waves
// = 16 waves/CU (same residency). XCD map: one batch per XCD (K/V L2-resident).
__global__ __launch_bounds__(512)
void attn_kernel(const short* __restrict__ qkv, const int* __restrict__ amask,
                 short* __restrict__ out)
{
  __shared__ __align__(16) char lsm[36864];
  char* lsK = lsm;
  char* lsV = lsm + 16384;
  int* lmask = (int*)(lsm + 32768);
  __shared__ int anym;

  const int tid = threadIdx.x;
  const int lane = tid & 63;
  const int w = tid >> 6;           // 0..7
  const int l31 = lane & 31;
  const int hi = lane >> 5;
  const int swz = (l31 & 7) << 4;

  // 512 blocks: xcd = bid&7 -> b; qt fastest within XCD
  const int bid = blockIdx.x;
  const int swzb = ((bid & 7) << 6) | (bid >> 3);
  const int qt = swzb & 3;
  const int h = (swzb >> 2) & 15;
  const int b = swzb >> 6;
  const size_t rowbase = (size_t)b * SEQ;
  const short* qkvB = qkv + rowbase * 3072 + h * 64;

  // mask: 1024 ints over 512 threads (int2) + any-zero flag
  const int2 mv = ((const int2*)(amask + b * SEQ))[tid];
  if (tid == 0) anym = 0;
  ((int2*)lmask)[tid] = mv;
  __syncthreads();
  if ((mv.x & mv.y) == 0) atomicOr(&anym, 1);

  // Q hoist: wave's q row = qt*256 + w*32 + l31
  const int q0 = qt * 256 + w * 32;
  const short* qptr = qkvB + (size_t)(q0 + l31) * 3072;
  short8 qf[4];
#pragma unroll
  for (int ks = 0; ks < 4; ++ks)
    qf[ks] = *(const short8*)(qptr + ks * 16 + hi * 8);

  // staging: 512 threads -> 1 K gload + 1 V vector load (8 scatter stores) each
  const int krow = tid >> 3;                                   // 0..63
  const int kcc = (((tid & 7) * 16) ^ ((krow & 7) << 4)) >> 1; // preswizzled col
  const short* gK = qkvB + 1024 + kcc;
  char* ldK = lsK + tid * 16;
  const int vr = tid & 63;                                     // kv row
  const int vc0 = (tid >> 6) << 3;                             // 0..56
  const short* gV = qkvB + 2048 + vc0;

  // stage chunk 0
  gload16(gK + (size_t)krow * 3072, ldK);
  {
    short8 a0 = *(const short8*)(gV + (size_t)vr * 3072);
#pragma unroll
    for (int j = 0; j < 8; ++j)
      *(short*)(lsV + (vc0 + j) * 128 + ((2 * vr) ^ (j << 4))) = a0[j];
  }
  __syncthreads();

  f32x16 oacc[2] = {};
  float psum = 0.f;

  for (int c = 0; c < 16; ++c) {
    const int cur = c & 1;
    const char* lKc = lsK + cur * 8192;
    const char* lVc = lsV + cur * 8192;
    const bool pf = (c < 15);
    short8 vv0;
    if (pf) {
      const size_t nb_ = (size_t)(c + 1) * 64;
      gload16(gK + (nb_ + krow) * 3072, ldK + (cur ^ 1) * 8192);
      vv0 = *(const short8*)(gV + (nb_ + vr) * 3072);
    }

    // QK^T (swapped): pacc[s] = S^T[32kv x 32q]
    f32x16 pacc[2] = {};
    __builtin_amdgcn_s_setprio(1);
#pragma unroll
    for (int ks = 0; ks < 4; ++ks) {
#pragma unroll
      for (int s = 0; s < 2; ++s) {
        short8 kf = *(const short8*)(lKc + (s * 32 + l31) * 128 +
                                     ((ks * 32 + hi * 16) ^ swz));
        pacc[s] = mfma32(kf, qf[ks], pacc[s]);
      }
    }
    __builtin_amdgcn_s_setprio(0);

    // V scatter for next chunk (latency hidden under QK^T)
    if (pf) {
      char* lVn = lsV + (cur ^ 1) * 8192;
#pragma unroll
      for (int j = 0; j < 8; ++j)
        *(short*)(lVn + (vc0 + j) * 128 + ((2 * vr) ^ (j << 4))) = vv0[j];
    }

    if (anym) {
      const int kv0 = c * 64;
#pragma unroll
      for (int s = 0; s < 2; ++s)
#pragma unroll
        for (int r = 0; r < 16; ++r) {
          const int kv = kv0 + 32 * s + (r & 3) + 8 * (r >> 2) + 4 * hi;
          if (lmask[kv] == 0) pacc[s][r] = -1e30f;
        }
    }

    // P = exp2(S) (Q pre-scaled) + row-sum
    float pe[2][16];
#pragma unroll
    for (int s = 0; s < 2; ++s)
#pragma unroll
      for (int r = 0; r < 16; ++r) {
        const float p = __builtin_amdgcn_exp2f(pacc[s][r]);
        pe[s][r] = p;
        psum += p;
      }

    // pack P -> bf16 A-fragments: cvt_pk + permlane32_swap
    short8 pa[4];
#pragma unroll
    for (int ks = 0; ks < 4; ++ks) {
      const int sh = ks >> 1, kb = (ks & 1) << 3;
      unsigned int aa = cvtpk(pe[sh][kb + 0], pe[sh][kb + 1]);
      unsigned int bb = cvtpk(pe[sh][kb + 4], pe[sh][kb + 5]);
      unsigned int cc = cvtpk(pe[sh][kb + 2], pe[sh][kb + 3]);
      unsigned int dd = cvtpk(pe[sh][kb + 6], pe[sh][kb + 7]);
      asm volatile("v_permlane32_swap_b32 %0, %1" : "+v"(aa), "+v"(bb));
      asm volatile("v_permlane32_swap_b32 %0, %1" : "+v"(cc), "+v"(dd));
      u32x4 t;
      t[0] = aa; t[1] = cc; t[2] = bb; t[3] = dd;
      pa[ks] = __builtin_bit_cast(short8, t);
    }

    // PV
    __builtin_amdgcn_s_setprio(1);
#pragma unroll
    for (int nb = 0; nb < 2; ++nb)
#pragma unroll
      for (int ks = 0; ks < 4; ++ks) {
        short8 vf = *(const short8*)(lVc + (nb * 32 + l31) * 128 +
                                     ((ks * 32 + hi * 16) ^ swz));
        oacc[nb] = mfma32(pa[ks], vf, oacc[nb]);
      }
    __builtin_amdgcn_s_setprio(0);

    __syncthreads();
  }

  const float lt = psum + __shfl_xor(psum, 32);
  const size_t orow = rowbase + q0;
#pragma unroll
  for (int r = 0; r < 16; ++r) {
    const int q = (r & 3) + 8 * (r >> 2) + 4 * hi;
    const float linv = 1.0f / __shfl(lt, q);
    short* op = out + (orow + q) * DIMC + h * 64 + l31;
    op[0]  = f2bf(oacc[0][r] * linv);
    op[32] = f2bf(oacc[1][r] * linv);
  }
}

// ---------------- orchestration ----------------
extern "C" void kernel_launch(void* const* d_in, const int* in_sizes, int n_in,
                              void* d_out, int out_size, void* d_ws, size_t ws_size,
                              hipStream_t stream)
{
  const float* x      = (const float*)d_in[0];
  const int*   amask  = (const int*)d_in[1];
  const float* ln1_g  = (const float*)d_in[2];
  const float* ln1_b  = (const float*)d_in[3];
  const float* qkv_w  = (const float*)d_in[4];
  const float* proj_w = (const float*)d_in[5];
  const float* proj_b = (const float*)d_in[6];
  const float* ln2_g  = (const float*)d_in[7];
  const float* ln2_b  = (const float*)d_in[8];
  const float* fc1_w  = (const float*)d_in[9];
  const float* fc1_b  = (const float*)d_in[10];
  const float* fc2_w  = (const float*)d_in[11];
  const float* fc2_b  = (const float*)d_in[12];
  float* out = (float*)d_out;

  char* ws = (char*)d_ws;
  short* wqkv  = (short*)(ws);
  short* wproj = (short*)(ws + 6291456);
  short* wfc1  = (short*)(ws + 8388608);
  short* wfc2  = (short*)(ws + 16777216);
  short* x1b   = (short*)(ws + 25165824);   // bf16 residual trunk
  short* hb    = (short*)(ws + 58720256);
  short* qkvo  = (short*)(ws + 75497472);
  short* attno = (short*)(ws + 125829120);
  short* fc1o  = (short*)(ws + 75497472);   // aliases qkvo+attno (dead by then)

  // merged: LN1 (8192 blocks) + all weight converts (12288 blocks)
  prep_kernel<<<NROWS + 12288, 256, 0, stream>>>(
      x, ln1_g, ln1_b, hb, qkv_w, proj_w, fc1_w, fc2_w,
      wqkv, wproj, wfc1, wfc2);

  // QKV: M=8192 N=3072 K=1024 -> 768 blocks (gemm2k), Q cols pre-scaled
  gemm2k<false, false, false, false, true, true><<<768, 512, 0, stream>>>(
      hb, wqkv, nullptr, nullptr, nullptr, qkvo, NROWS, 3 * DIMC, DIMC, 24, 4);

  attn_kernel<<<512, 512, 0, stream>>>(qkvo, amask, attno);

  // proj + bias + residual(x f32) -> x1b (bf16): 256 blocks (gemm2k)
  gemm2k<true, false, true, false, true, false><<<256, 512, 0, stream>>>(
      attno, wproj, proj_b, x, nullptr, x1b, NROWS, DIMC, DIMC, 8, 4);

  // LN2 on bf16 trunk
  ln_kernel<true><<<NROWS, 256, 0, stream>>>(x1b, ln2_g, ln2_b, hb);

  // FC1 + bias + gelu: N=4096, BN=256 -> 512 blocks (gemm8p)
  gemm8p<true, true, false, true><<<512, 512, 0, stream>>>(
      hb, wfc1, fc1_b, nullptr, nullptr, fc1o, NROWS, MLPHID, DIMC, 16, 4);

  // FC2 + bias + residual(x1b bf16) -> out (f32): K=4096, 256 blocks (gemm2k)
  gemm2k<true, false, true, true, false, false><<<256, 512, 0, stream>>>(
      fc1o, wfc2, fc2_b, x1b, out, nullptr, NROWS, DIMC, MLPHID, 8, 4);
}

// Round 14
// 305.137 us; speedup vs baseline: 1.0649x; 1.0046x over previous
//
#include <hip/hip_runtime.h>
#include <hip/hip_bf16.h>
#include <stdint.h>
#include <math.h>

#define DIMC 1024
#define SEQ 1024
#define NBATCH 8
#define NHEADS 16
#define HDIM 64
#define MLPHID 4096
#define NROWS (NBATCH*SEQ)

typedef __attribute__((ext_vector_type(8))) short short8;
typedef __attribute__((ext_vector_type(4))) float f32x4;
typedef __attribute__((ext_vector_type(16))) float f32x16;
typedef __attribute__((ext_vector_type(4))) unsigned int u32x4;

__device__ __forceinline__ short f2bf(float f) {
  union { float f; uint32_t u; } x; x.f = f;
  uint32_t r = (x.u + 0x7FFFu + ((x.u >> 16) & 1u)) >> 16;
  return (short)r;
}

__device__ __forceinline__ float bf2f(unsigned short b) {
  union { uint32_t u; float f; } c; c.u = ((uint32_t)b) << 16;
  return c.f;
}

__device__ __forceinline__ unsigned int cvtpk(float lo, float hi_) {
  unsigned int r;
  asm("v_cvt_pk_bf16_f32 %0, %1, %2" : "=v"(r) : "v"(lo), "v"(hi_));
  return r;
}

// tanh-form GELU via hw exp2 + rcp
__device__ __forceinline__ float gelu_f(float v) {
  const float t = v * v;
  const float p = fmaf(t, 0.044715f, 1.0f);
  const float e = __builtin_amdgcn_exp2f(2.3022082f * v * p);
  return v - v * __builtin_amdgcn_rcpf(e + 1.0f);
}

__device__ __forceinline__ f32x4 mfma16(short8 a, short8 b, f32x4 c) {
  return __builtin_amdgcn_mfma_f32_16x16x32_bf16(a, b, c, 0, 0, 0);
}
__device__ __forceinline__ f32x16 mfma32(short8 a, short8 b, f32x16 c) {
  return __builtin_amdgcn_mfma_f32_32x32x16_bf16(a, b, c, 0, 0, 0);
}

__device__ __forceinline__ void gload16(const void* g, void* l) {
  __builtin_amdgcn_global_load_lds(
      (const __attribute__((address_space(1))) uint32_t*)g,
      (__attribute__((address_space(3))) uint32_t*)l, 16, 0, 0);
}

// -------- merged prep: LN1 (blocks 0..8191) + weight converts (8192..20479) --------
__global__ __launch_bounds__(256)
void prep_kernel(const float* __restrict__ x, const float* __restrict__ g,
                 const float* __restrict__ beta, short* __restrict__ hb,
                 const float* __restrict__ w0, const float* __restrict__ w1,
                 const float* __restrict__ w2, const float* __restrict__ w3,
                 short* __restrict__ o0, short* __restrict__ o1,
                 short* __restrict__ o2, short* __restrict__ o3) {
  const int tid = threadIdx.x;
  if (blockIdx.x < NROWS) {
    const int row = blockIdx.x;
    const float4 v = ((const float4*)(x + (size_t)row * DIMC))[tid];
    float s = v.x + v.y + v.z + v.w;
    float q = v.x*v.x + v.y*v.y + v.z*v.z + v.w*v.w;
#pragma unroll
    for (int o = 32; o > 0; o >>= 1) { s += __shfl_down(s, o); q += __shfl_down(q, o); }
    __shared__ float rs[4], rq[4];
    const int lane = tid & 63, w = tid >> 6;
    if (lane == 0) { rs[w] = s; rq[w] = q; }
    __syncthreads();
    s = rs[0] + rs[1] + rs[2] + rs[3];
    q = rq[0] + rq[1] + rq[2] + rq[3];
    const float mean = s * (1.0f / DIMC);
    const float var = q * (1.0f / DIMC) - mean * mean;
    const float rstd = rsqrtf(var + 1e-5f);
    const float4 gv = ((const float4*)g)[tid];
    const float4 bv = ((const float4*)beta)[tid];
    short4 o4;
    o4.x = f2bf((v.x - mean) * rstd * gv.x + bv.x);
    o4.y = f2bf((v.y - mean) * rstd * gv.y + bv.y);
    o4.z = f2bf((v.z - mean) * rstd * gv.z + bv.z);
    o4.w = f2bf((v.w - mean) * rstd * gv.w + bv.w);
    ((short4*)(hb + (size_t)row * DIMC))[tid] = o4;
  } else {
    const int i = (blockIdx.x - NROWS) * 256 + tid;
    const float4* src;
    short4* dst;
    if (i < 786432)       { src = (const float4*)w0 + i;             dst = (short4*)o0 + i; }
    else if (i < 1048576) { src = (const float4*)w1 + (i - 786432);  dst = (short4*)o1 + (i - 786432); }
    else if (i < 2097152) { src = (const float4*)w2 + (i - 1048576); dst = (short4*)o2 + (i - 1048576); }
    else                  { src = (const float4*)w3 + (i - 2097152); dst = (short4*)o3 + (i - 2097152); }
    const float4 v = *src;
    short4 o;
    o.x = f2bf(v.x); o.y = f2bf(v.y); o.z = f2bf(v.z); o.w = f2bf(v.w);
    *dst = o;
  }
}

// ---------------- LayerNorm (row = 1024), bf16 input -> bf16 ----------------
template<bool INBF16>
__global__ __launch_bounds__(256)
void ln_kernel(const void* __restrict__ xin, const float* __restrict__ g,
               const float* __restrict__ beta, short* __restrict__ out) {
  const int row = blockIdx.x;
  const int tid = threadIdx.x;
  float4 v;
  if (INBF16) {
    const short4 vb = ((const short4*)xin)[row * 256 + tid];
    v.x = bf2f((unsigned short)vb.x); v.y = bf2f((unsigned short)vb.y);
    v.z = bf2f((unsigned short)vb.z); v.w = bf2f((unsigned short)vb.w);
  } else {
    v = ((const float4*)xin)[row * 256 + tid];
  }
  float s = v.x + v.y + v.z + v.w;
  float q = v.x*v.x + v.y*v.y + v.z*v.z + v.w*v.w;
#pragma unroll
  for (int o = 32; o > 0; o >>= 1) { s += __shfl_down(s, o); q += __shfl_down(q, o); }
  __shared__ float rs[4], rq[4];
  const int lane = tid & 63, w = tid >> 6;
  if (lane == 0) { rs[w] = s; rq[w] = q; }
  __syncthreads();
  s = rs[0] + rs[1] + rs[2] + rs[3];
  q = rq[0] + rq[1] + rq[2] + rq[3];
  const float mean = s * (1.0f / DIMC);
  const float var = q * (1.0f / DIMC) - mean * mean;
  const float rstd = rsqrtf(var + 1e-5f);
  const float4 gv = ((const float4*)g)[tid];
  const float4 bv = ((const float4*)beta)[tid];
  short4 o4;
  o4.x = f2bf((v.x - mean) * rstd * gv.x + bv.x);
  o4.y = f2bf((v.y - mean) * rstd * gv.y + bv.y);
  o4.z = f2bf((v.z - mean) * rstd * gv.z + bv.z);
  o4.w = f2bf((v.w - mean) * rstd * gv.w + bv.w);
  ((short4*)(out + (size_t)row * DIMC))[tid] = o4;
}

// ======================= GEMM engines (round-12 verified: 2 barriers/phase) =======================
// The trailing barrier is REQUIRED: stages with 1-phase reuse distance (e.g.
// gemm2k ph3's A-slot0 overwrite after ph2's ard0 reads) race without it —
// a fast wave's global_load_lds data can land before a skewed wave's ds_read
// returns (round-13 failure, absmax 0.346). Do not re-remove.

#define NOVM ((void)0)
#define NOST ((void)0)
#define FENCE asm volatile("" ::: "memory")
#define VMC4 asm volatile("s_waitcnt vmcnt(4)" ::: "memory")
#define VMC2 asm volatile("s_waitcnt vmcnt(2)" ::: "memory")

// ---------- gemm8p (FC1): BM=256/BN=256, 8 waves 2Mx4N, LDS 128KB ----------
#define SA(DB, H, T) \
  gload16(sA0 + (H)*hstep + (size_t)(T)*64, stb + ((DB)*4 + (H))*16384); \
  gload16(sA1 + (H)*hstep + (size_t)(T)*64, stb + ((DB)*4 + (H))*16384 + 8192)

#define SB(DB, H, T) \
  gload16(sB0 + (H)*hstep + (size_t)(T)*64, stb + ((DB)*4 + 2 + (H))*16384); \
  gload16(sB1 + (H)*hstep + (size_t)(T)*64, stb + ((DB)*4 + 2 + (H))*16384 + 8192)

#define PH(DB, QA, QB, LDA, LDB, STAGE, VM) \
  do { \
    if (LDB) { \
      _Pragma("unroll") \
      for (int ni = 0; ni < 2; ++ni) { \
        _Pragma("unroll") \
        for (int ks = 0; ks < 2; ++ks) \
          bfv[QB][ni][ks] = *(const short8*)(brd##DB + (((QB)*2 + ni)*2 + ks)*1024); \
      } \
    } \
    if (LDA) { \
      _Pragma("unroll") \
      for (int mi = 0; mi < 4; ++mi) { \
        _Pragma("unroll") \
        for (int ks = 0; ks < 2; ++ks) \
          af[mi][ks] = *(const short8*)(ard##DB + (((QA)*4 + mi)*2 + ks)*1024); \
      } \
    } \
    STAGE; \
    FENCE; \
    __builtin_amdgcn_s_barrier(); \
    FENCE; \
    __builtin_amdgcn_s_setprio(1); \
    _Pragma("unroll") \
    for (int ks = 0; ks < 2; ++ks) { \
      _Pragma("unroll") \
      for (int mi = 0; mi < 4; ++mi) { \
        _Pragma("unroll") \
        for (int ni = 0; ni < 2; ++ni) \
          acc[(QA)*4 + mi][(QB)*2 + ni] = \
            mfma16(af[mi][ks], bfv[QB][ni][ks], acc[(QA)*4 + mi][(QB)*2 + ni]); \
      } \
    } \
    __builtin_amdgcn_s_setprio(0); \
    VM; \
    FENCE; \
    __builtin_amdgcn_s_barrier(); \
    FENCE; \
  } while (0)

template<bool BIAS, bool GELU, bool RESID, bool OBF16>
__global__ __launch_bounds__(512)
void gemm8p(const short* __restrict__ A, const short* __restrict__ W,
            const float* __restrict__ bias, const float* __restrict__ resid,
            float* __restrict__ outF, short* __restrict__ outB,
            int M, int N, int K, int ntl, int mt8)
{
  __shared__ __align__(16) char lsm[131072];
  const int tid = threadIdx.x;
  const int lane = tid & 63;
  const int w = tid >> 6;
  const int wm = w >> 2;
  const int wn = w & 3;
  const int fr = lane & 15;
  const int fko = (lane >> 4) << 3;

  const int bid = blockIdx.x;
  const int xcd = bid & 7, l = bid >> 3;
  const int bm = (xcd * mt8 + l / ntl) << 8;
  const int bn = (l % ntl) << 8;

  int row_[2], kk_[2];
#pragma unroll
  for (int j = 0; j < 2; ++j) {
    const int s = j * 8 + (tid >> 6);
    const int r16 = (tid & 63) >> 2;
    const int cb = ((tid & 3) << 4) ^ (((tid >> 5) & 1) << 5);
    row_[j] = (s >> 1) * 16 + r16;
    kk_[j]  = (s & 1) * 32 + (cb >> 1);
  }
  const short* sA0 = A + (size_t)(bm + row_[0]) * K + kk_[0];
  const short* sA1 = A + (size_t)(bm + row_[1]) * K + kk_[1];
  const short* sB0 = W + (size_t)(bn + row_[0]) * K + kk_[0];
  const short* sB1 = W + (size_t)(bn + row_[1]) * K + kk_[1];
  const size_t hstep = (size_t)128 * K;
  char* stb = lsm + tid * 16;

  const int lofs = fr * 64 + ((fko << 1) ^ (((fr >> 3) & 1) << 5));
  const char* ard0 = lsm + wm * 16384 + lofs;
  const char* brd0 = lsm + 32768 + (wn >> 1) * 16384 + (wn & 1) * 8192 + lofs;
  const char* ard1 = ard0 + 65536;
  const char* brd1 = brd0 + 65536;

  short8 af[4][2];
  short8 bfv[2][2][2];
  f32x4 acc[8][4] = {};

  SA(0, 0, 0); SA(0, 1, 0);
  SB(0, 0, 0); SB(0, 1, 0);
  SB(1, 0, 1); SB(1, 1, 1);
  VMC4;
  __builtin_amdgcn_s_barrier();
  FENCE;

  const int nk = K >> 6;
  const int nit = nk >> 1;
  const int tmask = nk - 1;
  for (int it = 0; it < nit; ++it) {
    const int t1 = 2 * it + 1;
    const int t2 = (2 * it + 2) & tmask;
    const int t3 = (2 * it + 3) & tmask;
    PH(0, 0, 0, 1, 1, SA(1, 0, t1), NOVM);
    PH(0, 0, 1, 0, 1, SA(1, 1, t1), NOVM);
    PH(0, 1, 1, 1, 0, SB(0, 0, t2), NOVM);
    PH(0, 1, 0, 0, 0, SB(0, 1, t2), VMC4);
    PH(1, 0, 0, 1, 1, SA(0, 0, t2), NOVM);
    PH(1, 0, 1, 0, 1, SA(0, 1, t2), NOVM);
    PH(1, 1, 1, 1, 0, SB(1, 0, t3), NOVM);
    PH(1, 1, 0, 0, 0, SB(1, 1, t3), VMC4);
  }

  asm volatile("s_waitcnt vmcnt(0)" ::: "memory");
  __builtin_amdgcn_s_barrier();
  FENCE;

  const int orow0 = bm + wm * 128 + ((lane >> 4) << 2);
  const int ocol0 = bn + wn * 64 + fr;
#pragma unroll
  for (int mi = 0; mi < 8; ++mi) {
#pragma unroll
    for (int r = 0; r < 4; ++r) {
      const int row = orow0 + mi * 16 + r;
      const size_t base = (size_t)row * N;
#pragma unroll
      for (int ni = 0; ni < 4; ++ni) {
        const int col = ocol0 + ni * 16;
        float v = acc[mi][ni][r];
        if (BIAS) v += bias[col];
        if (GELU) v = gelu_f(v);
        if (RESID) v += resid[base + col];
        if (OBF16) outB[base + col] = f2bf(v);
        else       outF[base + col] = v;
      }
    }
  }
}

// ---------- gemm2k: BM=256/BN=128, by-ks phases (16 MFMA + 8 ds_read/phase) ----------
#define SAK(SLOT, T) \
  gload16(sA0 + (size_t)(T)*64,         (SLOT) + tid*16); \
  gload16(sA1 + (size_t)(T)*64,         (SLOT) + 8192 + tid*16); \
  gload16(sA0 + hstep + (size_t)(T)*64, (SLOT) + 16384 + tid*16); \
  gload16(sA1 + hstep + (size_t)(T)*64, (SLOT) + 24576 + tid*16)

#define SBK(SLOT, T) \
  gload16(sB0 + (size_t)(T)*64, (SLOT) + tid*16); \
  gload16(sB1 + (size_t)(T)*64, (SLOT) + 8192 + tid*16)

#define PHK(ARD, BRD, KS, STAGE, VM) \
  do { \
    _Pragma("unroll") \
    for (int jn = 0; jn < 4; ++jn) \
      bfq[jn] = *(const short8*)((BRD) + (jn*2 + (KS))*1024); \
    _Pragma("unroll") \
    for (int mi = 0; mi < 4; ++mi) \
      af[mi] = *(const short8*)((ARD) + (mi*2 + (KS))*1024); \
    STAGE; \
    FENCE; \
    __builtin_amdgcn_s_barrier(); \
    FENCE; \
    __builtin_amdgcn_s_setprio(1); \
    _Pragma("unroll") \
    for (int mi = 0; mi < 4; ++mi) { \
      _Pragma("unroll") \
      for (int jn = 0; jn < 4; ++jn) \
        acc[mi][jn] = mfma16(af[mi], bfq[jn], acc[mi][jn]); \
    } \
    __builtin_amdgcn_s_setprio(0); \
    VM; \
    FENCE; \
    __builtin_amdgcn_s_barrier(); \
    FENCE; \
  } while (0)

template<bool BIAS, bool GELU, bool RESID, bool RESB16, bool OBF16, bool QSCALE>
__global__ __launch_bounds__(512)
void gemm2k(const short* __restrict__ A, const short* __restrict__ W,
            const float* __restrict__ bias, const void* __restrict__ resid,
            float* __restrict__ outF, short* __restrict__ outB,
            int M, int N, int K, int ntl, int mt8)
{
  __shared__ __align__(16) char lsm[114688];
  const int tid = threadIdx.x;
  const int lane = tid & 63;
  const int w = tid >> 6;
  const int wm = w >> 1;
  const int wn = w & 1;
  const int fr = lane & 15;
  const int fko = (lane >> 4) << 3;

  const int bid = blockIdx.x;
  const int xcd = bid & 7, l = bid >> 3;
  const int bm = (xcd * mt8 + l / ntl) << 8;
  const int bn = (l % ntl) << 7;

  int row_[2], kk_[2];
#pragma unroll
  for (int j = 0; j < 2; ++j) {
    const int s = j * 8 + (tid >> 6);
    const int r16 = (tid & 63) >> 2;
    const int cb = ((tid & 3) << 4) ^ (((tid >> 5) & 1) << 5);
    row_[j] = (s >> 1) * 16 + r16;
    kk_[j]  = (s & 1) * 32 + (cb >> 1);
  }
  const short* sA0 = A + (size_t)(bm + row_[0]) * K + kk_[0];
  const short* sA1 = A + (size_t)(bm + row_[1]) * K + kk_[1];
  const short* sB0 = W + (size_t)(bn + row_[0]) * K + kk_[0];
  const short* sB1 = W + (size_t)(bn + row_[1]) * K + kk_[1];
  const size_t hstep = (size_t)128 * K;

  const int lofs = fr * 64 + ((fko << 1) ^ (((fr >> 3) & 1) << 5));
  const char* ard0 = lsm + wm * 8192 + lofs;
  const char* ard1 = ard0 + 32768;
  char* as0 = lsm;
  char* as1 = lsm + 32768;
  const char* bur = lsm + 65536 + 0 * 16384 + wn * 8192 + lofs;
  const char* bvr = lsm + 65536 + 1 * 16384 + wn * 8192 + lofs;
  const char* bwr = lsm + 65536 + 2 * 16384 + wn * 8192 + lofs;
  char* bus = lsm + 65536 + 0 * 16384;
  char* bvs = lsm + 65536 + 1 * 16384;
  char* bws = lsm + 65536 + 2 * 16384;

  short8 af[4];
  short8 bfq[4];
  f32x4 acc[4][4] = {};

  const int nk = K >> 6;
  const int nit = nk >> 1;
  const int tmask = nk - 1;

  SAK(as0, 0);
  SBK(bus, 0);
  SBK(bvs, 1);
  asm volatile("s_waitcnt vmcnt(0)" ::: "memory");
  __builtin_amdgcn_s_barrier();
  FENCE;

  for (int it = 0; it < nit; ++it) {
    const int v  = 2 * it + 1;
    const int t2 = (2 * it + 2) & tmask;
    const int t3 = (2 * it + 3) & tmask;
    PHK(ard0, bur, 0, SAK(as1, v),  NOVM);
    PHK(ard0, bur, 1, SBK(bws, t2), VMC2);
    PHK(ard1, bvr, 0, SAK(as0, t2), NOVM);
    PHK(ard1, bvr, 1, SBK(bus, t3), VMC2);
    const char* tr;
    tr = bur; bur = bwr; bwr = bvr; bvr = tr;
    char* ts;
    ts = bus; bus = bws; bws = bvs; bvs = ts;
  }

  asm volatile("s_waitcnt vmcnt(0)" ::: "memory");
  __builtin_amdgcn_s_barrier();
  FENCE;

  const int orow0 = bm + wm * 64 + ((lane >> 4) << 2);
  const int ocol0 = bn + wn * 64 + fr;
#pragma unroll
  for (int mi = 0; mi < 4; ++mi) {
#pragma unroll
    for (int r = 0; r < 4; ++r) {
      const int row = orow0 + mi * 16 + r;
      const size_t base = (size_t)row * N;
#pragma unroll
      for (int ni = 0; ni < 4; ++ni) {
        const int col = ocol0 + ni * 16;
        float v = acc[mi][ni][r];
        if (BIAS) v += bias[col];
        if (GELU) v = gelu_f(v);
        if (QSCALE) v *= (col < 1024 ? 0.18033688f : 1.0f);  // Q *= scale*log2e
        if (RESID) {
          if (RESB16) v += bf2f(((const unsigned short*)resid)[base + col]);
          else        v += ((const float*)resid)[base + col];
        }
        if (OBF16) outB[base + col] = f2bf(v);
        else       outF[base + col] = v;
      }
    }
  }
}

// ---------------- Flash attention, 8 waves x 32 q-rows (256 q/block) ----------------
__global__ __launch_bounds__(512)
void attn_kernel(const short* __restrict__ qkv, const int* __restrict__ amask,
                 short* __restrict__ out)
{
  __shared__ __align__(16) char lsm[36864];
  char* lsK = lsm;
  char* lsV = lsm + 16384;
  int* lmask = (int*)(lsm + 32768);
  __shared__ int anym;

  const int tid = threadIdx.x;
  const int lane = tid & 63;
  const int w = tid >> 6;
  const int l31 = lane & 31;
  const int hi = lane >> 5;
  const int swz = (l31 & 7) << 4;

  const int bid = blockIdx.x;
  const int swzb = ((bid & 7) << 6) | (bid >> 3);
  const int qt = swzb & 3;
  const int h = (swzb >> 2) & 15;
  const int b = swzb >> 6;
  const size_t rowbase = (size_t)b * SEQ;
  const short* qkvB = qkv + rowbase * 3072 + h * 64;

  const int2 mv = ((const int2*)(amask + b * SEQ))[tid];
  if (tid == 0) anym = 0;
  ((int2*)lmask)[tid] = mv;
  __syncthreads();
  if ((mv.x & mv.y) == 0) atomicOr(&anym, 1);

  const int q0 = qt * 256 + w * 32;
  const short* qptr = qkvB + (size_t)(q0 + l31) * 3072;
  short8 qf[4];
#pragma unroll
  for (int ks = 0; ks < 4; ++ks)
    qf[ks] = *(const short8*)(qptr + ks * 16 + hi * 8);

  const int krow = tid >> 3;
  const int kcc = (((tid & 7) * 16) ^ ((krow & 7) << 4)) >> 1;
  const short* gK = qkvB + 1024 + kcc;
  char* ldK = lsK + tid * 16;
  const int vr = tid & 63;
  const int vc0 = (tid >> 6) << 3;
  const short* gV = qkvB + 2048 + vc0;

  gload16(gK + (size_t)krow * 3072, ldK);
  {
    short8 a0 = *(const short8*)(gV + (size_t)vr * 3072);
#pragma unroll
    for (int j = 0; j < 8; ++j)
      *(short*)(lsV + (vc0 + j) * 128 + ((2 * vr) ^ (j << 4))) = a0[j];
  }
  __syncthreads();

  f32x16 oacc[2] = {};
  float psum = 0.f;

  for (int c = 0; c < 16; ++c) {
    const int cur = c & 1;
    const char* lKc = lsK + cur * 8192;
    const char* lVc = lsV + cur * 8192;
    const bool pf = (c < 15);
    short8 vv0;
    if (pf) {
      const size_t nb_ = (size_t)(c + 1) * 64;
      gload16(gK + (nb_ + krow) * 3072, ldK + (cur ^ 1) * 8192);
      vv0 = *(const short8*)(gV + (nb_ + vr) * 3072);
    }

    f32x16 pacc[2] = {};
    __builtin_amdgcn_s_setprio(1);
#pragma unroll
    for (int ks = 0; ks < 4; ++ks) {
#pragma unroll
      for (int s = 0; s < 2; ++s) {
        short8 kf = *(const short8*)(lKc + (s * 32 + l31) * 128 +
                                     ((ks * 32 + hi * 16) ^ swz));
        pacc[s] = mfma32(kf, qf[ks], pacc[s]);
      }
    }
    __builtin_amdgcn_s_setprio(0);

    if (pf) {
      char* lVn = lsV + (cur ^ 1) * 8192;
#pragma unroll
      for (int j = 0; j < 8; ++j)
        *(short*)(lVn + (vc0 + j) * 128 + ((2 * vr) ^ (j << 4))) = vv0[j];
    }

    if (anym) {
      const int kv0 = c * 64;
#pragma unroll
      for (int s = 0; s < 2; ++s)
#pragma unroll
        for (int r = 0; r < 16; ++r) {
          const int kv = kv0 + 32 * s + (r & 3) + 8 * (r >> 2) + 4 * hi;
          if (lmask[kv] == 0) pacc[s][r] = -1e30f;
        }
    }

    float pe[2][16];
#pragma unroll
    for (int s = 0; s < 2; ++s)
#pragma unroll
      for (int r = 0; r < 16; ++r) {
        const float p = __builtin_amdgcn_exp2f(pacc[s][r]);
        pe[s][r] = p;
        psum += p;
      }

    short8 pa[4];
#pragma unroll
    for (int ks = 0; ks < 4; ++ks) {
      const int sh = ks >> 1, kb = (ks & 1) << 3;
      unsigned int aa = cvtpk(pe[sh][kb + 0], pe[sh][kb + 1]);
      unsigned int bb = cvtpk(pe[sh][kb + 4], pe[sh][kb + 5]);
      unsigned int cc = cvtpk(pe[sh][kb + 2], pe[sh][kb + 3]);
      unsigned int dd = cvtpk(pe[sh][kb + 6], pe[sh][kb + 7]);
      asm volatile("v_permlane32_swap_b32 %0, %1" : "+v"(aa), "+v"(bb));
      asm volatile("v_permlane32_swap_b32 %0, %1" : "+v"(cc), "+v"(dd));
      u32x4 t;
      t[0] = aa; t[1] = cc; t[2] = bb; t[3] = dd;
      pa[ks] = __builtin_bit_cast(short8, t);
    }

    __builtin_amdgcn_s_setprio(1);
#pragma unroll
    for (int nb = 0; nb < 2; ++nb)
#pragma unroll
      for (int ks = 0; ks < 4; ++ks) {
        short8 vf = *(const short8*)(lVc + (nb * 32 + l31) * 128 +
                                     ((ks * 32 + hi * 16) ^ swz));
        oacc[nb] = mfma32(pa[ks], vf, oacc[nb]);
      }
    __builtin_amdgcn_s_setprio(0);

    __syncthreads();
  }

  const float lt = psum + __shfl_xor(psum, 32);
  const size_t orow = rowbase + q0;
#pragma unroll
  for (int r = 0; r < 16; ++r) {
    const int q = (r & 3) + 8 * (r >> 2) + 4 * hi;
    const float linv = 1.0f / __shfl(lt, q);
    short* op = out + (orow + q) * DIMC + h * 64 + l31;
    op[0]  = f2bf(oacc[0][r] * linv);
    op[32] = f2bf(oacc[1][r] * linv);
  }
}

// ---------------- orchestration ----------------
extern "C" void kernel_launch(void* const* d_in, const int* in_sizes, int n_in,
                              void* d_out, int out_size, void* d_ws, size_t ws_size,
                              hipStream_t stream)
{
  const float* x      = (const float*)d_in[0];
  const int*   amask  = (const int*)d_in[1];
  const float* ln1_g  = (const float*)d_in[2];
  const float* ln1_b  = (const float*)d_in[3];
  const float* qkv_w  = (const float*)d_in[4];
  const float* proj_w = (const float*)d_in[5];
  const float* proj_b = (const float*)d_in[6];
  const float* ln2_g  = (const float*)d_in[7];
  const float* ln2_b  = (const float*)d_in[8];
  const float* fc1_w  = (const float*)d_in[9];
  const float* fc1_b  = (const float*)d_in[10];
  const float* fc2_w  = (const float*)d_in[11];
  const float* fc2_b  = (const float*)d_in[12];
  float* out = (float*)d_out;

  char* ws = (char*)d_ws;
  short* wqkv  = (short*)(ws);
  short* wproj = (short*)(ws + 6291456);
  short* wfc1  = (short*)(ws + 8388608);
  short* wfc2  = (short*)(ws + 16777216);
  short* x1b   = (short*)(ws + 25165824);   // bf16 residual trunk
  short* hb    = (short*)(ws + 58720256);
  short* qkvo  = (short*)(ws + 75497472);
  short* attno = (short*)(ws + 125829120);
  short* fc1o  = (short*)(ws + 75497472);   // aliases qkvo+attno (dead by then)

  // merged: LN1 (8192 blocks) + all weight converts (12288 blocks)
  prep_kernel<<<NROWS + 12288, 256, 0, stream>>>(
      x, ln1_g, ln1_b, hb, qkv_w, proj_w, fc1_w, fc2_w,
      wqkv, wproj, wfc1, wfc2);

  // QKV: M=8192 N=3072 K=1024 -> 768 blocks (gemm2k), Q cols pre-scaled
  gemm2k<false, false, false, false, true, true><<<768, 512, 0, stream>>>(
      hb, wqkv, nullptr, nullptr, nullptr, qkvo, NROWS, 3 * DIMC, DIMC, 24, 4);

  attn_kernel<<<512, 512, 0, stream>>>(qkvo, amask, attno);

  // proj + bias + residual(x f32) -> x1b (bf16): 256 blocks (gemm2k)
  gemm2k<true, false, true, false, true, false><<<256, 512, 0, stream>>>(
      attno, wproj, proj_b, x, nullptr, x1b, NROWS, DIMC, DIMC, 8, 4);

  // LN2 on bf16 trunk
  ln_kernel<true><<<NROWS, 256, 0, stream>>>(x1b, ln2_g, ln2_b, hb);

  // FC1 + bias + gelu: N=4096, BN=256 -> 512 blocks (gemm8p)
  gemm8p<true, true, false, true><<<512, 512, 0, stream>>>(
      hb, wfc1, fc1_b, nullptr, nullptr, fc1o, NROWS, MLPHID, DIMC, 16, 4);

  // FC2 + bias + residual(x1b bf16) -> out (f32): K=4096, 256 blocks (gemm2k)
  gemm2k<true, false, true, true, false, false><<<256, 512, 0, stream>>>(
      fc1o, wfc2, fc2_b, x1b, out, nullptr, NROWS, DIMC, MLPHID, 8, 4);
}